// Round 7
// baseline (440.309 us; speedup 1.0000x reference)
//
#include <hip/hip_runtime.h>
#include <hip/hip_bf16.h>
#include <math.h>

// Problem constants
#define BATCH 8
#define CIN 16
#define HID 64
#define S2 1024            // 32*32
#define SP 4096            // 4*32*32 spatial elems per channel
#define CHB 262144         // HID*SP per batch
#define TAU 5
#define GATE_SZ 2097152    // BATCH*CHB floats = one gate buffer
#define EPS 1e-5f

// ws layout (floats): [0..3*GATE_SZ) = u4,u5,u6 ; [3G) Z ; [4G) stats(128 floats).
// Weight packs + PCM live in dead d_out slots (see kernel_launch).
#define WS_Z_OFF   ((size_t)3 * GATE_SZ)
#define WS_ST_OFF  ((size_t)4 * GATE_SZ)
// stats: scores[0..39] (l*8+b)

typedef unsigned short u16;
typedef __attribute__((ext_vector_type(8))) short  short8;
typedef __attribute__((ext_vector_type(8))) u16    ushort8;
typedef __attribute__((ext_vector_type(4))) float  f32x4;

#define N7 (7*27*64*96)
#define NO (27*64*128)
#define N1 (64*128)

__device__ __forceinline__ u16 f2b(float v) {
    __hip_bfloat16 h = __float2bfloat16(v);
    u16 r; __builtin_memcpy(&r, &h, 2); return r;
}

__device__ __forceinline__ float* gate_ptr(float* out, float* ws, int g) {
    return (g < 4) ? (out + (size_t)g * GATE_SZ) : (ws + (size_t)(g - 4) * GATE_SZ);
}

// fast activations: native v_exp_f32 via __expf, clamped so exp never overflows
__device__ __forceinline__ float fsig(float v) {
    v = fminf(fmaxf(v, -30.f), 30.f);
    return 1.f / (1.f + __expf(-v));
}
__device__ __forceinline__ float ftanh(float v) {
    v = fminf(fmaxf(v, -15.f), 15.f);
    const float t = __expf(-2.f * v);
    return (1.f - t) / (1.f + t);
}

// ---- weight pack: A7[g][tap][oc][96], Ao[tap][oc][128], A111[oc][128] (bf16) ----
// Also zeroes the scores-stats block and the LN3 sums table.
__global__ __launch_bounds__(256) void pack_w_k(const float* __restrict__ Wx,
                                                const float* __restrict__ Wh,
                                                const float* __restrict__ w111,
                                                u16* __restrict__ A7, u16* __restrict__ Ao,
                                                u16* __restrict__ A111,
                                                float* __restrict__ stats,
                                                float* __restrict__ sums)
{
    const int idx = blockIdx.x * 256 + threadIdx.x;
    if (idx < 128)  stats[idx] = 0.f;
    if (idx < 6144) sums[idx] = 0.f;     // 6 gates * 8 b * 64 oc * {s,s2}
    if (idx < N7) {
        const int k = idx % 96, oc = (idx / 96) % 64, tap = (idx / (96*64)) % 27, g = idx / (96*64*27);
        float v = 0.f;
        if (k < 16)      v = Wx[((size_t)(g*64 + oc)*16 + k)      * 27 + tap];
        else if (k < 80) v = Wh[((size_t)(g*64 + oc)*64 + (k-16)) * 27 + tap];
        A7[idx] = f2b(v);
    } else if (idx < N7 + NO) {
        const int j = idx - N7;
        const int k = j % 128, oc = (j / 128) % 64, tap = j / (128*64);
        float v = (k < 64) ? Wh[((size_t)(7*64 + oc)*64 + k)      * 27 + tap]
                           : Wh[((size_t)(8*64 + oc)*64 + (k-64)) * 27 + tap];
        Ao[j] = f2b(v);
    } else if (idx < N7 + NO + N1) {
        const int j = idx - N7 - NO;
        A111[j] = f2b(w111[j]);
    }
}

// ---- input pack: XH[b][4096][96], XM[b][4096][96] (bf16, ch-minor) ----
__global__ __launch_bounds__(256) void pack_xhm_k(const float* __restrict__ x,
                                                  const float* __restrict__ h,
                                                  const float* __restrict__ m,
                                                  u16* __restrict__ XH, u16* __restrict__ XM)
{
    __shared__ float t[144][65];
    const int bi = blockIdx.x, b = bi >> 6, s0 = (bi & 63) << 6;
    for (int i = threadIdx.x; i < 144*64; i += 256) {
        const int row = i >> 6, sc = i & 63;
        float v;
        if (row < 16)      v = x[((size_t)b*16 + row)      * SP + s0 + sc];
        else if (row < 80) v = h[((size_t)b*64 + (row-16)) * SP + s0 + sc];
        else               v = m[((size_t)b*64 + (row-80)) * SP + s0 + sc];
        t[row][sc] = v;
    }
    __syncthreads();
    for (int j = threadIdx.x; j < 64*96; j += 256) {
        const int s = j / 96, ch = j % 96;
        const size_t o = ((size_t)b*4096 + s0 + s) * 96 + ch;
        XH[o] = f2b(ch < 80 ? t[ch][s] : 0.f);
        XM[o] = f2b(ch < 16 ? t[ch][s] : (ch < 80 ? t[ch + 64][s] : 0.f));
    }
}

// LDS XOR swizzle: 16B column-block c (0..3) of row r lands at block c^((r>>1)&3).
// Applied identically on staging store and fragment read -> bijective; verified
// round 1: SQ_LDS_BANK_CONFLICT 4.6M -> 0.
__device__ __forceinline__ int swz32(int r, int c) {
    return r * 32 + ((c ^ ((r >> 1) & 3)) << 3);
}

// ---- implicit-GEMM conv via MFMA 16x16x32 bf16 ----
// MODE 0: 7 gate convs (K=96, 27 taps, X = XH or XM per gate, bias bx+bh, write)
//         MT=4, MINW=3 (R0's proven 148-reg config) with the COMPILE-TIME
//         kd-outer / 9-tap-unrolled-inner loop (R4's low-VALU structure).
//         Round-6 lesson: runtime tap indices -> VALU 42%, 132 us. Taps must be
//         compile-time so swz32/weight addresses fold to immediates.
//         Epilogue accumulates LN3 sums (s, s2) per (g,b,oc) via shfl + atomics.
// MODE 1: o-gate state conv (K=128, 27 taps, X=PCM, read-add-store, NO atomics).
//         OC-SPLIT MT=2 -> grid 512 = 2 blocks/CU at MINW=4 (was 1/CU, 4 waves —
//         latency-starved). oc partition keeps read-add-store race-free.
// MODE 2: 1x1x1 conv (K=128, 1 tap, X=PCM, bias b111, write into ws slot 0).
//         Weight pack has ONE tap -> index tap 0 (round-5 bug).
template<int KCH, int TAPS, int NR, int MODE, int MT, int MINW>
__global__ __launch_bounds__(256, MINW) void conv_mfma_k(
    const u16* __restrict__ XA, const u16* __restrict__ XB,
    const u16* __restrict__ Apack,
    const float* __restrict__ bxp, const float* __restrict__ bhp,
    const float* __restrict__ b111,
    float* __restrict__ out, float* __restrict__ ws,
    float* __restrict__ sums)
{
    constexpr int YT   = NR + 2;        // y rows in tile (with halo)
    constexpr int ROWS = 4 * YT * 34;   // t * y * x(with halo)
    __shared__ __align__(16) u16 xs[ROWS * 32];

    const int bi = blockIdx.x;
    int g = 0, b, y0, ocb = 0, kc_lo = 0, kc_hi = KCH / 32;
    const u16* X; const u16* Ag; float* outp;
    if (MODE == 0) {
        constexpr int YB = 32 / NR;
        if (MT == 2) {
            ocb = (bi & 1) * 32;
            const int r2 = bi >> 1;
            g = r2 / (8 * YB); b = (r2 / YB) % 8; y0 = (r2 % YB) * NR;
        } else {
            g = bi / (8 * YB); b = (bi / YB) % 8; y0 = (bi % YB) * NR;
        }
        X  = (g >= 3 && g <= 5) ? XB : XA;
        Ag = Apack + (size_t)g * TAPS * 64 * KCH;
        outp = gate_ptr(out, ws, g) + (size_t)b * CHB;
    } else if (MODE == 1) {
        if (MT == 2) { ocb = (bi & 1) * 32; b = bi >> 6; y0 = (bi >> 1) & 31; }
        else         { b = bi >> 5; y0 = bi & 31; }
        X = XA; Ag = Apack;
        outp = ws + (size_t)2 * GATE_SZ + (size_t)b * CHB;
    } else {
        b = bi >> 5; y0 = bi & 31;
        X = XA; Ag = Apack;
        outp = ws + (size_t)b * CHB;
    }
    const u16* Xb = X + (size_t)b * 4096 * KCH;

    const int tid  = threadIdx.x;
    const int w    = tid >> 6;          // wave = output t-plane
    const int lane = tid & 63;
    const int xn   = lane & 15, quad = lane >> 4;

    f32x4 acc[MT][2 * NR] = {};

    for (int kc = kc_lo; kc < kc_hi; ++kc) {
        if (kc != kc_lo) __syncthreads();
        // stage 32-channel slab of the (t, y-halo, x-halo) tile into LDS (swizzled)
        for (int cix = tid; cix < ROWS * 4; cix += 256) {
            const int r = cix >> 2, sub = cix & 3;
            const int t = r / (YT * 34), rem = r % (YT * 34);
            const int yy = rem / 34, xx = rem % 34;
            const int gy = y0 + yy - 1, gx = xx - 1;
            ushort8 v = {0, 0, 0, 0, 0, 0, 0, 0};
            if ((unsigned)gy < 32u && (unsigned)gx < 32u)
                v = *(const ushort8*)&Xb[(size_t)(t * 1024 + gy * 32 + gx) * KCH + kc * 32 + sub * 8];
            *(ushort8*)&xs[swz32(r, sub)] = v;
        }
        __syncthreads();

        if (TAPS == 27) {
            // kd runtime (2-3 iters), inner 9 (ky,kx) COMPILE-TIME unrolled:
            // all LDS/weight offsets fold to immediates, scheduler pipelines.
            const int kd_lo = (w == 0) ? 1 : 0;
            const int kd_hi = (w == 3) ? 2 : 3;
            for (int kd = kd_lo; kd < kd_hi; ++kd) {
                const int rowt = (w + kd - 1) * YT * 34;
                #pragma unroll
                for (int jj = 0; jj < 9; ++jj) {
                    const int ky = jj / 3, kx = jj % 3;     // compile-time
                    short8 a[MT], bf[2 * NR];
                    #pragma unroll
                    for (int mt = 0; mt < MT; ++mt)
                        a[mt] = *(const short8*)
                            &Ag[(size_t)((kd * 9 + jj) * 64 + ocb + mt * 16 + xn) * KCH + kc * 32 + quad * 8];
                    #pragma unroll
                    for (int nt = 0; nt < 2 * NR; ++nt) {
                        const int ysub = nt >> 1, xh = nt & 1;
                        const int row = rowt + (ysub + ky) * 34 + xh * 16 + xn + kx;
                        bf[nt] = *(const short8*)&xs[swz32(row, quad)];
                    }
                    #pragma unroll
                    for (int nt = 0; nt < 2 * NR; ++nt)
                        #pragma unroll
                        for (int mt = 0; mt < MT; ++mt)
                            acc[mt][nt] = __builtin_amdgcn_mfma_f32_16x16x32_bf16(a[mt], bf[nt], acc[mt][nt], 0, 0, 0);
                }
            }
        } else {
            // single center tap (kd=ky=kx=1); weight pack has only tap 0
            short8 a[MT], bf[2 * NR];
            #pragma unroll
            for (int mt = 0; mt < MT; ++mt)
                a[mt] = *(const short8*)&Ag[(size_t)(ocb + mt * 16 + xn) * KCH + kc * 32 + quad * 8];
            #pragma unroll
            for (int nt = 0; nt < 2 * NR; ++nt) {
                const int ysub = nt >> 1, xh = nt & 1;
                const int row = (w * YT + ysub + 1) * 34 + xh * 16 + xn + 1;
                bf[nt] = *(const short8*)&xs[swz32(row, quad)];
            }
            #pragma unroll
            for (int nt = 0; nt < 2 * NR; ++nt)
                #pragma unroll
                for (int mt = 0; mt < MT; ++mt)
                    acc[mt][nt] = __builtin_amdgcn_mfma_f32_16x16x32_bf16(a[mt], bf[nt], acc[mt][nt], 0, 0, 0);
        }
    }

    // epilogue: C/D layout col=lane&15, row=quad*4+reg
    #pragma unroll
    for (int mt = 0; mt < MT; ++mt)
    #pragma unroll
    for (int nt = 0; nt < 2 * NR; ++nt) {
        const int ysub = nt >> 1, xh = nt & 1;
        const int sp = w * 1024 + (y0 + ysub) * 32 + xh * 16 + xn;
        #pragma unroll
        for (int reg = 0; reg < 4; ++reg) {
            const int oc = ocb + mt * 16 + quad * 4 + reg;
            float bias;
            if (MODE == 0)      bias = bxp[g * 64 + oc] + bhp[g * 64 + oc];
            else if (MODE == 1) bias = bhp[7 * 64 + oc] + bhp[8 * 64 + oc];
            else                bias = b111[oc];
            float* p = outp + (size_t)oc * SP + sp;
            float vv = acc[mt][nt][reg] + bias;
            if (MODE == 1) vv += *p;     // accumulate onto MODE-0 g6 output; each
            *p = vv;                     // element owned by exactly one block
        }
    }

    // LN3 partial sums (gates 0..5 only; u6 is finalized by MODE 1 / ln3_act_k)
    if (MODE == 0 && g < 6) {
        #pragma unroll
        for (int mt = 0; mt < MT; ++mt)
        #pragma unroll
        for (int reg = 0; reg < 4; ++reg) {
            const int oc = ocb + mt * 16 + quad * 4 + reg;
            const float bias = bxp[g * 64 + oc] + bhp[g * 64 + oc];
            float s = 0.f, s2 = 0.f;
            #pragma unroll
            for (int nt = 0; nt < 2 * NR; ++nt) {
                const float vv = acc[mt][nt][reg] + bias;
                s += vv; s2 += vv * vv;
            }
            #pragma unroll
            for (int off = 8; off > 0; off >>= 1) {
                s  += __shfl_xor(s, off);       // butterfly within the 16-lane xn group
                s2 += __shfl_xor(s2, off);
            }
            if (xn == 0) {
                float* dst = &sums[(size_t)((g * 8 + b) * 64 + oc) * 2];
                atomicAdd(dst, s);
                atomicAdd(dst + 1, s2);
            }
        }
    }
}

// ---- LayerNorm + activation in place (gate 6 / o-gate only) ----
__global__ __launch_bounds__(256) void ln3_act_k(float* __restrict__ out,
                                                 float* __restrict__ ws, int gate0)
{
    const int blk = blockIdx.x;
    const int g = gate0 + (blk >> 9);
    float* p = gate_ptr(out, ws, g) + (size_t)(blk & 511) * SP;
    const int tid = threadIdx.x;

    float s = 0.f, s2 = 0.f;
    for (int k = tid; k < SP; k += 256) { float v = p[k]; s += v; s2 += v * v; }
    #pragma unroll
    for (int off = 32; off > 0; off >>= 1) { s += __shfl_down(s, off); s2 += __shfl_down(s2, off); }
    __shared__ float rs[4], rs2[4], stat[2];
    if ((tid & 63) == 0) { rs[tid >> 6] = s; rs2[tid >> 6] = s2; }
    __syncthreads();
    if (tid == 0) {
        float S  = rs[0] + rs[1] + rs[2] + rs[3];
        float Sq = rs2[0] + rs2[1] + rs2[2] + rs2[3];
        float mu  = S * (1.f / SP);
        float var = Sq * (1.f / SP) - mu * mu;
        stat[0] = mu; stat[1] = rsqrtf(var + EPS);
    }
    __syncthreads();
    const float mu = stat[0], r = stat[1];
    for (int k = tid; k < SP; k += 256)
        p[k] = fsig((p[k] - mu) * r);           // gate 6 is sigmoid
}

// ---- attention scores: sigma(LN(u0)) applied on the fly; one r-read, 5 dots ----
__global__ __launch_bounds__(256) void scores_k(const float* __restrict__ u0,
                                                const float* __restrict__ chist,
                                                const float* __restrict__ sums,
                                                float* __restrict__ stats)
{
    const int blk = blockIdx.x;            // 512 = 8 b * 64 chn (chunk == channel)
    const int b = blk >> 6, chn = blk & 63;
    const float* sp2 = &sums[(size_t)(b * 64 + chn) * 2];   // g = 0
    const float mu = sp2[0] * (1.f / SP);
    const float var = sp2[1] * (1.f / SP) - mu * mu;
    const float rr = rsqrtf(var + EPS);
    const float* rp = u0 + (size_t)b * CHB;
    const int lo = chn * SP;
    float s[TAU] = {};
    for (int k = lo + threadIdx.x; k < lo + SP; k += 256) {
        const float rv = fsig((rp[k] - mu) * rr);
        #pragma unroll
        for (int l = 0; l < TAU; ++l) s[l] += rv * chist[(size_t)(l * BATCH + b) * CHB + k];
    }
    __shared__ float rsh[TAU][4];
    #pragma unroll
    for (int l = 0; l < TAU; ++l) {
        float v = s[l];
        #pragma unroll
        for (int off = 32; off > 0; off >>= 1) v += __shfl_down(v, off);
        if ((threadIdx.x & 63) == 0) rsh[l][threadIdx.x >> 6] = v;
    }
    __syncthreads();
    if (threadIdx.x < TAU) {
        const int l = threadIdx.x;
        atomicAdd(&stats[l * 8 + b],
                  (rsh[l][0] + rsh[l][1] + rsh[l][2] + rsh[l][3]) * (1.f / 64.f));
    }
}

// ---- z = chist[4,b] + sum_l attn[b,l]*chist[l,b]; softmax fused; per-block partials ----
__global__ __launch_bounds__(256) void recall_k(const float* __restrict__ chist,
                                                float* __restrict__ ws,
                                                float* __restrict__ part)
{
    const float* stats = ws + WS_ST_OFF;
    const int blk = blockIdx.x;
    const int b = blk >> 10;
    const int idx = (blk & 1023) * 256 + threadIdx.x;

    // softmax over dim 0 (batch) of scores[l*8+b], per l — 5 threads, broadcast via LDS
    __shared__ float attn[TAU];
    if (threadIdx.x < TAU) {
        const int l = threadIdx.x;
        float mx = -1e30f;
        for (int bb = 0; bb < BATCH; ++bb) mx = fmaxf(mx, stats[l * 8 + bb]);
        float sum = 0.f, e = 0.f;
        for (int bb = 0; bb < BATCH; ++bb) {
            float t = __expf(stats[l * 8 + bb] - mx);
            sum += t;
            if (bb == b) e = t;
        }
        attn[l] = e / sum;
    }
    __syncthreads();
    const float a0 = attn[0], a1 = attn[1], a2 = attn[2], a3 = attn[3], a4 = attn[4];

    const size_t e = (size_t)b * CHB + idx;
    const size_t LB = (size_t)BATCH * CHB;
    float z = chist[4 * LB + e] * (1.f + a4)
            + a0 * chist[0 * LB + e] + a1 * chist[1 * LB + e]
            + a2 * chist[2 * LB + e] + a3 * chist[3 * LB + e];
    ws[WS_Z_OFF + e] = z;

    float s = z, s2 = z * z;
    #pragma unroll
    for (int off = 32; off > 0; off >>= 1) { s += __shfl_down(s, off); s2 += __shfl_down(s2, off); }
    __shared__ float rs[4], rs2[4];
    if ((threadIdx.x & 63) == 0) { rs[threadIdx.x >> 6] = s; rs2[threadIdx.x >> 6] = s2; }
    __syncthreads();
    if (threadIdx.x == 0) {
        part[blk]        = rs[0] + rs[1] + rs[2] + rs[3];
        part[8192 + blk] = rs2[0] + rs2[1] + rs2[2] + rs2[3];
    }
}

// ---- fused: LN4 stats + LN3+act of gates 1..5 on the fly + c,m_new + PCM pack ----
__global__ __launch_bounds__(256) void cm_pcm_k(float* __restrict__ out, float* __restrict__ ws,
                                                const float* __restrict__ m,
                                                const float* __restrict__ lnw,
                                                const float* __restrict__ lnb,
                                                const float* __restrict__ part,
                                                const float* __restrict__ sums,
                                                u16* __restrict__ PCM)
{
    __shared__ __align__(16) u16 tl[64][136];   // [sp][128 ch + pad], 16B-aligned rows
    __shared__ float lst[5][64][2];             // LN3 stats for gates 1..5, this batch
    const int bi = blockIdx.x;
    const int b = bi >> 6;
    const int s0 = (bi & 63) << 6;

    // LN3 stats (gates 1..5) from raw sums + re-reduce the 1024 LN4 partials
    for (int j = threadIdx.x; j < 5 * 64; j += 256) {
        const int gg = j >> 6, chn = j & 63;
        const float* sp2 = &sums[(size_t)(((gg + 1) * 8 + b) * 64 + chn) * 2];
        const float mu_ = sp2[0] * (1.f / SP);
        const float var_ = sp2[1] * (1.f / SP) - mu_ * mu_;
        lst[gg][chn][0] = mu_;
        lst[gg][chn][1] = rsqrtf(var_ + EPS);
    }
    float s = 0.f, s2 = 0.f;
    for (int j = threadIdx.x; j < 1024; j += 256) {
        s  += part[b * 1024 + j];
        s2 += part[8192 + b * 1024 + j];
    }
    #pragma unroll
    for (int off = 32; off > 0; off >>= 1) { s += __shfl_down(s, off); s2 += __shfl_down(s2, off); }
    __shared__ float rs[4], rs2[4], st[2];
    if ((threadIdx.x & 63) == 0) { rs[threadIdx.x >> 6] = s; rs2[threadIdx.x >> 6] = s2; }
    __syncthreads();
    if (threadIdx.x == 0) {
        float S  = rs[0] + rs[1] + rs[2] + rs[3];
        float Sq = rs2[0] + rs2[1] + rs2[2] + rs2[3];
        float mu  = S * (1.f / CHB);
        float var = Sq * (1.f / CHB) - mu * mu;
        st[0] = mu; st[1] = rsqrtf(var + EPS);
    }
    __syncthreads();
    const float mu = st[0], rstd = st[1];

    for (int i = threadIdx.x; i < 1024; i += 256) {       // 64ch x 16 float4
        const int chn = i >> 4;
        const int sp4 = (i & 15) << 2;
        const size_t e = (size_t)b * CHB + (size_t)chn * SP + s0 + sp4;
        const size_t le = (size_t)chn * SP + s0 + sp4;
        float4 z  = *(const float4*)&ws[WS_Z_OFF + e];
        float4 u1 = *(const float4*)&gate_ptr(out, ws, 1)[e];
        float4 u2 = *(const float4*)&gate_ptr(out, ws, 2)[e];
        float4 u3 = *(const float4*)&gate_ptr(out, ws, 3)[e];
        float4 u4 = *(const float4*)&gate_ptr(out, ws, 4)[e];
        float4 u5 = *(const float4*)&gate_ptr(out, ws, 5)[e];
        float4 mm = *(const float4*)&m[e];
        float4 lw = *(const float4*)&lnw[le];
        float4 lb = *(const float4*)&lnb[le];
        const float m1 = lst[0][chn][0], r1 = lst[0][chn][1];
        const float m2 = lst[1][chn][0], r2 = lst[1][chn][1];
        const float m3 = lst[2][chn][0], r3 = lst[2][chn][1];
        const float m4 = lst[3][chn][0], r4 = lst[3][chn][1];
        const float m5 = lst[4][chn][0], r5 = lst[4][chn][1];
        float4 c, mn;
        {
            const float uu1[4] = {u1.x, u1.y, u1.z, u1.w};
            const float uu2[4] = {u2.x, u2.y, u2.z, u2.w};
            const float uu3[4] = {u3.x, u3.y, u3.z, u3.w};
            const float uu4[4] = {u4.x, u4.y, u4.z, u4.w};
            const float uu5[4] = {u5.x, u5.y, u5.z, u5.w};
            const float zz[4]  = {z.x, z.y, z.z, z.w};
            const float mmv[4] = {mm.x, mm.y, mm.z, mm.w};
            const float lwv[4] = {lw.x, lw.y, lw.z, lw.w};
            const float lbv[4] = {lb.x, lb.y, lb.z, lb.w};
            float cv[4], mv[4];
            #pragma unroll
            for (int k = 0; k < 4; ++k) {
                const float gi = fsig ((uu1[k] - m1) * r1);
                const float gg = ftanh((uu2[k] - m2) * r2);
                const float ip = fsig ((uu3[k] - m3) * r3);
                const float gp = ftanh((uu4[k] - m4) * r4);
                const float fp = fsig ((uu5[k] - m5) * r5);
                cv[k] = gi * gg + (zz[k] - mu) * rstd * lwv[k] + lbv[k];
                mv[k] = ip * gp + fp * mmv[k];
                tl[sp4 + k][chn]      = f2b(cv[k]);
                tl[sp4 + k][64 + chn] = f2b(mv[k]);
            }
            c.x = cv[0]; c.y = cv[1]; c.z = cv[2]; c.w = cv[3];
            mn.x = mv[0]; mn.y = mv[1]; mn.z = mv[2]; mn.w = mv[3];
        }
        *(float4*)&out[(size_t)4 * GATE_SZ + e] = c;
        *(float4*)&out[(size_t)5 * GATE_SZ + e] = mn;
    }
    __syncthreads();
    for (int j = threadIdx.x; j < 1024; j += 256) {       // 64 s x 16 ushort8
        const int sidx = j >> 4, c8 = (j & 15) << 3;
        ushort8 v = *(const ushort8*)&tl[sidx][c8];
        *(ushort8*)&PCM[((size_t)b * 4096 + s0 + sidx) * 128 + c8] = v;
    }
}

// ---- merged tail: c_history_new[0:4] = c_history[1:5]  AND  h_new = o * tanh(v) ----
__global__ __launch_bounds__(256) void tail_k(const float* __restrict__ chist,
                                              const float* __restrict__ o,
                                              const float* __restrict__ v,
                                              float* __restrict__ out)
{
    const int bi = blockIdx.x;
    if (bi < 8192) {
        const size_t i = (size_t)bi * 256 + threadIdx.x;
        ((float4*)out)[i] = ((const float4*)(chist + GATE_SZ))[i];
    } else {
        const size_t i = (size_t)(bi - 8192) * 256 + threadIdx.x;
        float4 ov = ((const float4*)o)[i], vv = ((const float4*)v)[i];
        float4 r;
        r.x = ov.x * ftanh(vv.x); r.y = ov.y * ftanh(vv.y);
        r.z = ov.z * ftanh(vv.z); r.w = ov.w * ftanh(vv.w);
        ((float4*)(out + (size_t)6 * GATE_SZ))[i] = r;
    }
}

extern "C" void kernel_launch(void* const* d_in, const int* in_sizes, int n_in,
                              void* d_out, int out_size, void* d_ws, size_t ws_size,
                              hipStream_t stream)
{
    const float* x    = (const float*)d_in[0];
    const float* ch   = (const float*)d_in[1];
    const float* m    = (const float*)d_in[2];
    const float* h    = (const float*)d_in[3];
    const float* Wx   = (const float*)d_in[4];
    const float* bx   = (const float*)d_in[5];
    const float* Wh   = (const float*)d_in[6];
    const float* bh   = (const float*)d_in[7];
    const float* w111 = (const float*)d_in[8];
    const float* b111 = (const float*)d_in[9];
    const float* lnw  = (const float*)d_in[10];
    const float* lnb  = (const float*)d_in[11];
    float* out = (float*)d_out;
    float* ws  = (float*)d_ws;

    // Scratch placement in DEAD d_out slots (ws stays within the proven
    // 4*GATE_SZ+128-float footprint):
    //   slot 0: u0 (raw r) until scores_k; then PCM (8 MB) written by cm_pcm_k,
    //           read by conv MODE 1/2, finally overwritten by tail_k (hist copy).
    //   slot 4: XH (6 MB) dead after MODE 0; slot rewritten by cm_pcm_k with c.
    //   slot 5: A7 (2.2 MB) dead after MODE 0; rewritten by cm_pcm_k (m_new).
    //   slot 6: XM (6 MB) + Ao/A111 (0.46 MB) + LN4 partials (64 KB) + LN3 sums
    //           (24 KB) — all consumed before tail_k writes h_new at the end.
    u16* XH   = (u16*)(out + (size_t)4 * GATE_SZ);
    u16* A7   = (u16*)(out + (size_t)5 * GATE_SZ);
    u16* XM   = (u16*)(out + (size_t)6 * GATE_SZ);
    u16* Ao   = XM + (size_t)BATCH * 4096 * 96;      // behind XM, same slot
    u16* A111 = Ao + (size_t)NO;
    u16* PCM  = (u16*)out;                           // slot 0 (dead after scores_k)
    float* part = (float*)(A111 + N1);               // 16384 floats, slot-6 dead zone
    float* sums = part + 16384;                      // 6144 floats, slot-6 dead zone
    float* stats = ws + WS_ST_OFF;

    pack_w_k<<<(N7 + NO + N1 + 255) / 256, 256, 0, stream>>>(Wx, Wh, w111, A7, Ao, A111, stats, sums);
    pack_xhm_k<<<512, 256, 0, stream>>>(x, h, m, XH, XM);

    // MODE 0: MT=4, 3 blocks/CU, compile-time taps, LN3 sums in epilogue
    conv_mfma_k<96, 27, 2, 0, 4, 3><<<896, 256, 0, stream>>>(XH, XM, A7, bx, bh, nullptr, out, ws, sums);

    scores_k<<<512, 256, 0, stream>>>(out, ch, sums, stats);         // sigma(LN(u0)) inline
    recall_k<<<8192, 256, 0, stream>>>(ch, ws, part);                // softmax fused
    cm_pcm_k<<<512, 256, 0, stream>>>(out, ws, m, lnw, lnb, part, sums, PCM);

    // MODE 1: oc-split MT=2 -> 512 blocks = 2/CU (was 1/CU, latency-starved)
    conv_mfma_k<128, 27, 1, 1, 2, 4><<<512, 256, 0, stream>>>(PCM, nullptr, Ao, nullptr, bh, nullptr, out, ws, nullptr);
    ln3_act_k<<<512, 256, 0, stream>>>(out, ws, 6);                  // gate 6 (o)
    conv_mfma_k<128, 1, 1, 2, 4, 3><<<256, 256, 0, stream>>>(PCM, nullptr, A111, nullptr, nullptr, b111, out, ws, nullptr);

    tail_k<<<10240, 256, 0, stream>>>(ch, ws + (size_t)2 * GATE_SZ, ws, out);
}

// Round 8
// 408.390 us; speedup vs baseline: 1.0782x; 1.0782x over previous
//
#include <hip/hip_runtime.h>
#include <hip/hip_bf16.h>
#include <math.h>

// Problem constants
#define BATCH 8
#define CIN 16
#define HID 64
#define S2 1024            // 32*32
#define SP 4096            // 4*32*32 spatial elems per channel
#define CHB 262144         // HID*SP per batch
#define TAU 5
#define GATE_SZ 2097152    // BATCH*CHB floats = one gate buffer
#define EPS 1e-5f

// ws layout (floats): [0..3*GATE_SZ) = u4,u5,u6 ; [3G) Z ; [4G) stats(128 floats).
// Weight packs + PCM live in dead d_out slots (see kernel_launch).
#define WS_Z_OFF   ((size_t)3 * GATE_SZ)
#define WS_ST_OFF  ((size_t)4 * GATE_SZ)
// stats: scores[0..39] (l*8+b)

typedef unsigned short u16;
typedef __attribute__((ext_vector_type(8))) short  short8;
typedef __attribute__((ext_vector_type(8))) u16    ushort8;
typedef __attribute__((ext_vector_type(4))) float  f32x4;

#define N7 (7*27*64*96)
#define NO (27*64*128)
#define N1 (64*128)

__device__ __forceinline__ u16 f2b(float v) {
    __hip_bfloat16 h = __float2bfloat16(v);
    u16 r; __builtin_memcpy(&r, &h, 2); return r;
}

__device__ __forceinline__ float* gate_ptr(float* out, float* ws, int g) {
    return (g < 4) ? (out + (size_t)g * GATE_SZ) : (ws + (size_t)(g - 4) * GATE_SZ);
}

// fast activations: native v_exp_f32 via __expf, clamped so exp never overflows
__device__ __forceinline__ float fsig(float v) {
    v = fminf(fmaxf(v, -30.f), 30.f);
    return 1.f / (1.f + __expf(-v));
}
__device__ __forceinline__ float ftanh(float v) {
    v = fminf(fmaxf(v, -15.f), 15.f);
    const float t = __expf(-2.f * v);
    return (1.f - t) / (1.f + t);
}

// ---- weight pack: A7[g][tap][oc][96], Ao[tap][oc][128], A111[oc][128] (bf16) ----
// Also zeroes the scores-stats block and the LN3 sums table (7 gates now).
__global__ __launch_bounds__(256) void pack_w_k(const float* __restrict__ Wx,
                                                const float* __restrict__ Wh,
                                                const float* __restrict__ w111,
                                                u16* __restrict__ A7, u16* __restrict__ Ao,
                                                u16* __restrict__ A111,
                                                float* __restrict__ stats,
                                                float* __restrict__ sums)
{
    const int idx = blockIdx.x * 256 + threadIdx.x;
    if (idx < 128)  stats[idx] = 0.f;
    if (idx < 7168) sums[idx] = 0.f;     // 7 gates * 8 b * 64 oc * {s,s2}
    if (idx < N7) {
        const int k = idx % 96, oc = (idx / 96) % 64, tap = (idx / (96*64)) % 27, g = idx / (96*64*27);
        float v = 0.f;
        if (k < 16)      v = Wx[((size_t)(g*64 + oc)*16 + k)      * 27 + tap];
        else if (k < 80) v = Wh[((size_t)(g*64 + oc)*64 + (k-16)) * 27 + tap];
        A7[idx] = f2b(v);
    } else if (idx < N7 + NO) {
        const int j = idx - N7;
        const int k = j % 128, oc = (j / 128) % 64, tap = j / (128*64);
        float v = (k < 64) ? Wh[((size_t)(7*64 + oc)*64 + k)      * 27 + tap]
                           : Wh[((size_t)(8*64 + oc)*64 + (k-64)) * 27 + tap];
        Ao[j] = f2b(v);
    } else if (idx < N7 + NO + N1) {
        const int j = idx - N7 - NO;
        A111[j] = f2b(w111[j]);
    }
}

// ---- input pack: XH[b][4096][96], XM[b][4096][96] (bf16, ch-minor) ----
__global__ __launch_bounds__(256) void pack_xhm_k(const float* __restrict__ x,
                                                  const float* __restrict__ h,
                                                  const float* __restrict__ m,
                                                  u16* __restrict__ XH, u16* __restrict__ XM)
{
    __shared__ float t[144][65];
    const int bi = blockIdx.x, b = bi >> 6, s0 = (bi & 63) << 6;
    for (int i = threadIdx.x; i < 144*64; i += 256) {
        const int row = i >> 6, sc = i & 63;
        float v;
        if (row < 16)      v = x[((size_t)b*16 + row)      * SP + s0 + sc];
        else if (row < 80) v = h[((size_t)b*64 + (row-16)) * SP + s0 + sc];
        else               v = m[((size_t)b*64 + (row-80)) * SP + s0 + sc];
        t[row][sc] = v;
    }
    __syncthreads();
    for (int j = threadIdx.x; j < 64*96; j += 256) {
        const int s = j / 96, ch = j % 96;
        const size_t o = ((size_t)b*4096 + s0 + s) * 96 + ch;
        XH[o] = f2b(ch < 80 ? t[ch][s] : 0.f);
        XM[o] = f2b(ch < 16 ? t[ch][s] : (ch < 80 ? t[ch + 64][s] : 0.f));
    }
}

// ---- implicit-GEMM conv via MFMA 16x16x32 bf16, runtime 2-deep pipelined taps ----
// Config ladder (measured): R0 runtime-dbuf+PADK40+MINW3+MT4 = 101 us (BEST);
// swizzle = 105 (XOR VALU > conflict cost); compile-time unroll at MT4 spills
// (R7: WRITE 57->115 MB); MT2 doubles staging (R4: 112). The explicit 2-deep
// buffer IS the register-pressure cap — do not replace it with full unrolls.
// MODE 0: 7 gate convs (K=96, 27 taps, XH/XM, bias bx+bh, write + LN3 sums g<6)
// MODE 1: o-gate state conv (K=128, 27 taps, PCM, read-add-store onto MODE-0 g6,
//         oc-split MT=2 grid 512 -> 2 blocks/CU; final u6 sums -> sums[g=6])
// MODE 2: 1x1x1 conv (K=128, 1 tap -> weight tap 0 (R5 bug), write v to ws slot 0)
template<int KCH, int TAPS, int NR, int MODE, int MT, int MINW>
__global__ __launch_bounds__(256, MINW) void conv_mfma_k(
    const u16* __restrict__ XA, const u16* __restrict__ XB,
    const u16* __restrict__ Apack,
    const float* __restrict__ bxp, const float* __restrict__ bhp,
    const float* __restrict__ b111,
    float* __restrict__ out, float* __restrict__ ws,
    float* __restrict__ sums)
{
    constexpr int YT   = NR + 2;        // y rows in tile (with halo)
    constexpr int ROWS = 4 * YT * 34;   // t * y * x(with halo)
    constexpr int PADK = 40;            // 80B rows, 16B aligned; conflicts cheaper than swizzle
    __shared__ __align__(16) u16 xs[ROWS * PADK];

    const int bi = blockIdx.x;
    int g = 0, b, y0, ocb = 0;
    const u16* X; const u16* Ag; float* outp;
    if (MODE == 0) {
        constexpr int YB = 32 / NR;
        g  = bi / (8 * YB);
        b  = (bi / YB) % 8;
        y0 = (bi % YB) * NR;
        X  = (g >= 3 && g <= 5) ? XB : XA;
        Ag = Apack + (size_t)g * TAPS * 64 * KCH;
        outp = gate_ptr(out, ws, g) + (size_t)b * CHB;
    } else if (MODE == 1) {
        ocb = (bi & 1) * 32;            // oc half (MT=2): grid 512 = 8b*32y*2oc
        b  = bi >> 6;
        y0 = (bi >> 1) & 31;
        X = XA; Ag = Apack;
        outp = ws + (size_t)2 * GATE_SZ + (size_t)b * CHB;
    } else {
        b = bi >> 5; y0 = bi & 31;
        X = XA; Ag = Apack;
        outp = ws + (size_t)b * CHB;
    }
    const u16* Xb = X + (size_t)b * 4096 * KCH;

    const int tid  = threadIdx.x;
    const int w    = tid >> 6;          // wave = output t-plane
    const int lane = tid & 63;
    const int xn   = lane & 15, quad = lane >> 4;

    f32x4 acc[MT][2 * NR] = {};

    for (int kc = 0; kc < KCH / 32; ++kc) {
        if (kc != 0) __syncthreads();
        // stage 32-channel slab of the (t, y-halo, x-halo) tile into LDS
        for (int cix = tid; cix < ROWS * 4; cix += 256) {
            const int r = cix >> 2, sub = cix & 3;
            const int t = r / (YT * 34), rem = r % (YT * 34);
            const int yy = rem / 34, xx = rem % 34;
            const int gy = y0 + yy - 1, gx = xx - 1;
            ushort8 v = {0, 0, 0, 0, 0, 0, 0, 0};
            if ((unsigned)gy < 32u && (unsigned)gx < 32u)
                v = *(const ushort8*)&Xb[(size_t)(t * 1024 + gy * 32 + gx) * KCH + kc * 32 + sub * 8];
            *(ushort8*)&xs[r * PADK + sub * 8] = v;
        }
        __syncthreads();

        auto load_a = [&](short8* a, int tap) {
            #pragma unroll
            for (int mt = 0; mt < MT; ++mt)
                a[mt] = *(const short8*)
                    &Ag[(size_t)(tap * 64 + ocb + mt * 16 + xn) * KCH + kc * 32 + quad * 8];
        };
        auto load_b = [&](short8* bf, int tap) {
            int kd, ky, kx;
            if (TAPS == 27) { kd = tap / 9; ky = (tap / 3) % 3; kx = tap % 3; }
            else            { kd = 1; ky = 1; kx = 1; }
            const int tin = w + kd - 1;
            #pragma unroll
            for (int nt = 0; nt < 2 * NR; ++nt) {
                const int ysub = nt >> 1, xh = nt & 1;
                bf[nt] = *(const short8*)
                    &xs[((tin * YT + ysub + ky) * 34 + xh * 16 + xn + kx) * PADK + quad * 8];
            }
        };
        auto do_mfma = [&](short8* a, short8* bf) {
            #pragma unroll
            for (int nt = 0; nt < 2 * NR; ++nt)
                #pragma unroll
                for (int mt = 0; mt < MT; ++mt)
                    acc[mt][nt] = __builtin_amdgcn_mfma_f32_16x16x32_bf16(a[mt], bf[nt], acc[mt][nt], 0, 0, 0);
        };

        if (TAPS == 27) {
            // valid taps form a contiguous range per wave (t-plane)
            const int tap_lo = (w == 0) ? 9 : 0;
            const int tap_hi = (w == 3) ? 18 : 27;
            short8 a0[MT], b0[2 * NR], a1[MT], b1[2 * NR];
            load_a(a0, tap_lo); load_b(b0, tap_lo);
            int tap = tap_lo;
            for (; tap + 2 <= tap_hi; tap += 2) {
                load_a(a1, tap + 1); load_b(b1, tap + 1);   // prefetch tap+1
                do_mfma(a0, b0);                            // compute tap
                if (tap + 2 < tap_hi) { load_a(a0, tap + 2); load_b(b0, tap + 2); }
                do_mfma(a1, b1);                            // compute tap+1
            }
            if (tap < tap_hi) do_mfma(a0, b0);              // odd tail
        } else {
            short8 a0[MT], b0[2 * NR];
            load_a(a0, 0); load_b(b0, 0);                   // 1-tap pack: weight tap 0
            do_mfma(a0, b0);
        }
    }

    // epilogue: C/D layout col=lane&15, row=quad*4+reg.
    // Restructured (mt,reg) outer so final vv (incl. MODE-1 read-add) feeds the
    // LN3 sums without a second pass. sums g<6 from MODE 0; g=6 from MODE 1.
    constexpr bool SUMS1 = (MODE == 1);
    #pragma unroll
    for (int mt = 0; mt < MT; ++mt)
    #pragma unroll
    for (int reg = 0; reg < 4; ++reg) {
        const int oc = ocb + mt * 16 + quad * 4 + reg;
        float bias;
        if (MODE == 0)      bias = bxp[g * 64 + oc] + bhp[g * 64 + oc];
        else if (MODE == 1) bias = bhp[7 * 64 + oc] + bhp[8 * 64 + oc];
        else                bias = b111[oc];
        float s = 0.f, s2 = 0.f;
        #pragma unroll
        for (int nt = 0; nt < 2 * NR; ++nt) {
            const int ysub = nt >> 1, xh = nt & 1;
            const int sp = w * 1024 + (y0 + ysub) * 32 + xh * 16 + xn;
            float* p = outp + (size_t)oc * SP + sp;
            float vv = acc[mt][nt][reg] + bias;
            if (MODE == 1) vv += *p;     // accumulate onto MODE-0 g6 output
            *p = vv;                     // each element owned by exactly one block
            s += vv; s2 += vv * vv;
        }
        if ((MODE == 0 && g < 6) || SUMS1) {
            #pragma unroll
            for (int off = 8; off > 0; off >>= 1) {
                s  += __shfl_xor(s, off);   // butterfly within the 16-lane xn group
                s2 += __shfl_xor(s2, off);
            }
            if (xn == 0) {
                const int gs = SUMS1 ? 6 : g;
                float* dst = &sums[(size_t)((gs * 8 + b) * 64 + oc) * 2];
                atomicAdd(dst, s);
                atomicAdd(dst + 1, s2);
            }
        }
    }
}

// ---- attention scores: sigma(LN(u0)) applied on the fly; one r-read, 5 dots ----
__global__ __launch_bounds__(256) void scores_k(const float* __restrict__ u0,
                                                const float* __restrict__ chist,
                                                const float* __restrict__ sums,
                                                float* __restrict__ stats)
{
    const int blk = blockIdx.x;            // 512 = 8 b * 64 chn (chunk == channel)
    const int b = blk >> 6, chn = blk & 63;
    const float* sp2 = &sums[(size_t)(b * 64 + chn) * 2];   // g = 0
    const float mu = sp2[0] * (1.f / SP);
    const float var = sp2[1] * (1.f / SP) - mu * mu;
    const float rr = rsqrtf(var + EPS);
    const float* rp = u0 + (size_t)b * CHB;
    const int lo = chn * SP;
    float s[TAU] = {};
    for (int k = lo + threadIdx.x; k < lo + SP; k += 256) {
        const float rv = fsig((rp[k] - mu) * rr);
        #pragma unroll
        for (int l = 0; l < TAU; ++l) s[l] += rv * chist[(size_t)(l * BATCH + b) * CHB + k];
    }
    __shared__ float rsh[TAU][4];
    #pragma unroll
    for (int l = 0; l < TAU; ++l) {
        float v = s[l];
        #pragma unroll
        for (int off = 32; off > 0; off >>= 1) v += __shfl_down(v, off);
        if ((threadIdx.x & 63) == 0) rsh[l][threadIdx.x >> 6] = v;
    }
    __syncthreads();
    if (threadIdx.x < TAU) {
        const int l = threadIdx.x;
        atomicAdd(&stats[l * 8 + b],
                  (rsh[l][0] + rsh[l][1] + rsh[l][2] + rsh[l][3]) * (1.f / 64.f));
    }
}

// ---- z = chist[4,b] + sum_l attn[b,l]*chist[l,b]; softmax fused; per-block partials ----
__global__ __launch_bounds__(256) void recall_k(const float* __restrict__ chist,
                                                float* __restrict__ ws,
                                                float* __restrict__ part)
{
    const float* stats = ws + WS_ST_OFF;
    const int blk = blockIdx.x;
    const int b = blk >> 10;
    const int idx = (blk & 1023) * 256 + threadIdx.x;

    // softmax over dim 0 (batch) of scores[l*8+b], per l — 5 threads, broadcast via LDS
    __shared__ float attn[TAU];
    if (threadIdx.x < TAU) {
        const int l = threadIdx.x;
        float mx = -1e30f;
        for (int bb = 0; bb < BATCH; ++bb) mx = fmaxf(mx, stats[l * 8 + bb]);
        float sum = 0.f, e = 0.f;
        for (int bb = 0; bb < BATCH; ++bb) {
            float t = __expf(stats[l * 8 + bb] - mx);
            sum += t;
            if (bb == b) e = t;
        }
        attn[l] = e / sum;
    }
    __syncthreads();
    const float a0 = attn[0], a1 = attn[1], a2 = attn[2], a3 = attn[3], a4 = attn[4];

    const size_t e = (size_t)b * CHB + idx;
    const size_t LB = (size_t)BATCH * CHB;
    float z = chist[4 * LB + e] * (1.f + a4)
            + a0 * chist[0 * LB + e] + a1 * chist[1 * LB + e]
            + a2 * chist[2 * LB + e] + a3 * chist[3 * LB + e];
    ws[WS_Z_OFF + e] = z;

    float s = z, s2 = z * z;
    #pragma unroll
    for (int off = 32; off > 0; off >>= 1) { s += __shfl_down(s, off); s2 += __shfl_down(s2, off); }
    __shared__ float rs[4], rs2[4];
    if ((threadIdx.x & 63) == 0) { rs[threadIdx.x >> 6] = s; rs2[threadIdx.x >> 6] = s2; }
    __syncthreads();
    if (threadIdx.x == 0) {
        part[blk]        = rs[0] + rs[1] + rs[2] + rs[3];
        part[8192 + blk] = rs2[0] + rs2[1] + rs2[2] + rs2[3];
    }
}

// ---- fused: LN4 stats + LN3+act of gates 1..5 on the fly + c,m_new + PCM pack ----
__global__ __launch_bounds__(256) void cm_pcm_k(float* __restrict__ out, float* __restrict__ ws,
                                                const float* __restrict__ m,
                                                const float* __restrict__ lnw,
                                                const float* __restrict__ lnb,
                                                const float* __restrict__ part,
                                                const float* __restrict__ sums,
                                                u16* __restrict__ PCM)
{
    __shared__ __align__(16) u16 tl[64][136];   // [sp][128 ch + pad], 16B-aligned rows
    __shared__ float lst[5][64][2];             // LN3 stats for gates 1..5, this batch
    const int bi = blockIdx.x;
    const int b = bi >> 6;
    const int s0 = (bi & 63) << 6;

    // LN3 stats (gates 1..5) from raw sums + re-reduce the 1024 LN4 partials
    for (int j = threadIdx.x; j < 5 * 64; j += 256) {
        const int gg = j >> 6, chn = j & 63;
        const float* sp2 = &sums[(size_t)(((gg + 1) * 8 + b) * 64 + chn) * 2];
        const float mu_ = sp2[0] * (1.f / SP);
        const float var_ = sp2[1] * (1.f / SP) - mu_ * mu_;
        lst[gg][chn][0] = mu_;
        lst[gg][chn][1] = rsqrtf(var_ + EPS);
    }
    float s = 0.f, s2 = 0.f;
    for (int j = threadIdx.x; j < 1024; j += 256) {
        s  += part[b * 1024 + j];
        s2 += part[8192 + b * 1024 + j];
    }
    #pragma unroll
    for (int off = 32; off > 0; off >>= 1) { s += __shfl_down(s, off); s2 += __shfl_down(s2, off); }
    __shared__ float rs[4], rs2[4], st[2];
    if ((threadIdx.x & 63) == 0) { rs[threadIdx.x >> 6] = s; rs2[threadIdx.x >> 6] = s2; }
    __syncthreads();
    if (threadIdx.x == 0) {
        float S  = rs[0] + rs[1] + rs[2] + rs[3];
        float Sq = rs2[0] + rs2[1] + rs2[2] + rs2[3];
        float mu  = S * (1.f / CHB);
        float var = Sq * (1.f / CHB) - mu * mu;
        st[0] = mu; st[1] = rsqrtf(var + EPS);
    }
    __syncthreads();
    const float mu = st[0], rstd = st[1];

    for (int i = threadIdx.x; i < 1024; i += 256) {       // 64ch x 16 float4
        const int chn = i >> 4;
        const int sp4 = (i & 15) << 2;
        const size_t e = (size_t)b * CHB + (size_t)chn * SP + s0 + sp4;
        const size_t le = (size_t)chn * SP + s0 + sp4;
        float4 z  = *(const float4*)&ws[WS_Z_OFF + e];
        float4 u1 = *(const float4*)&gate_ptr(out, ws, 1)[e];
        float4 u2 = *(const float4*)&gate_ptr(out, ws, 2)[e];
        float4 u3 = *(const float4*)&gate_ptr(out, ws, 3)[e];
        float4 u4 = *(const float4*)&gate_ptr(out, ws, 4)[e];
        float4 u5 = *(const float4*)&gate_ptr(out, ws, 5)[e];
        float4 mm = *(const float4*)&m[e];
        float4 lw = *(const float4*)&lnw[le];
        float4 lb = *(const float4*)&lnb[le];
        const float m1 = lst[0][chn][0], r1 = lst[0][chn][1];
        const float m2 = lst[1][chn][0], r2 = lst[1][chn][1];
        const float m3 = lst[2][chn][0], r3 = lst[2][chn][1];
        const float m4 = lst[3][chn][0], r4 = lst[3][chn][1];
        const float m5 = lst[4][chn][0], r5 = lst[4][chn][1];
        float4 c, mn;
        {
            const float uu1[4] = {u1.x, u1.y, u1.z, u1.w};
            const float uu2[4] = {u2.x, u2.y, u2.z, u2.w};
            const float uu3[4] = {u3.x, u3.y, u3.z, u3.w};
            const float uu4[4] = {u4.x, u4.y, u4.z, u4.w};
            const float uu5[4] = {u5.x, u5.y, u5.z, u5.w};
            const float zz[4]  = {z.x, z.y, z.z, z.w};
            const float mmv[4] = {mm.x, mm.y, mm.z, mm.w};
            const float lwv[4] = {lw.x, lw.y, lw.z, lw.w};
            const float lbv[4] = {lb.x, lb.y, lb.z, lb.w};
            float cv[4], mv[4];
            #pragma unroll
            for (int k = 0; k < 4; ++k) {
                const float gi = fsig ((uu1[k] - m1) * r1);
                const float gg = ftanh((uu2[k] - m2) * r2);
                const float ip = fsig ((uu3[k] - m3) * r3);
                const float gp = ftanh((uu4[k] - m4) * r4);
                const float fp = fsig ((uu5[k] - m5) * r5);
                cv[k] = gi * gg + (zz[k] - mu) * rstd * lwv[k] + lbv[k];
                mv[k] = ip * gp + fp * mmv[k];
                tl[sp4 + k][chn]      = f2b(cv[k]);
                tl[sp4 + k][64 + chn] = f2b(mv[k]);
            }
            c.x = cv[0]; c.y = cv[1]; c.z = cv[2]; c.w = cv[3];
            mn.x = mv[0]; mn.y = mv[1]; mn.z = mv[2]; mn.w = mv[3];
        }
        *(float4*)&out[(size_t)4 * GATE_SZ + e] = c;
        *(float4*)&out[(size_t)5 * GATE_SZ + e] = mn;
    }
    __syncthreads();
    for (int j = threadIdx.x; j < 1024; j += 256) {       // 64 s x 16 ushort8
        const int sidx = j >> 4, c8 = (j & 15) << 3;
        ushort8 v = *(const ushort8*)&tl[sidx][c8];
        *(ushort8*)&PCM[((size_t)b * 4096 + s0 + sidx) * 128 + c8] = v;
    }
}

// ---- merged tail: hist copy AND h_new = sig(LN(u6)) * tanh(v), o-gate LN fused ----
// (b,chn) is uniform per block (1024 consecutive elems within one 4096-elem chn),
// so u6's LN stats are 2 scalar loads from sums[g=6] (filled by MODE-1 epilogue).
__global__ __launch_bounds__(256) void tail_k(const float* __restrict__ chist,
                                              const float* __restrict__ u6,
                                              const float* __restrict__ v,
                                              const float* __restrict__ sums,
                                              float* __restrict__ out)
{
    const int bi = blockIdx.x;
    if (bi < 8192) {
        const size_t i = (size_t)bi * 256 + threadIdx.x;
        ((float4*)out)[i] = ((const float4*)(chist + GATE_SZ))[i];
    } else {
        const int j = bi - 8192;
        const size_t e0 = (size_t)j * 1024;
        const int b   = (int)(e0 >> 18);          // CHB = 2^18
        const int chn = (int)((e0 >> 12) & 63);   // SP  = 2^12
        const float* sp2 = &sums[(size_t)((6 * 8 + b) * 64 + chn) * 2];
        const float mu = sp2[0] * (1.f / SP);
        const float var = sp2[1] * (1.f / SP) - mu * mu;
        const float rr = rsqrtf(var + EPS);
        const size_t i = (size_t)j * 256 + threadIdx.x;
        float4 uv = ((const float4*)u6)[i], vv = ((const float4*)v)[i];
        float4 r;
        r.x = fsig((uv.x - mu) * rr) * ftanh(vv.x);
        r.y = fsig((uv.y - mu) * rr) * ftanh(vv.y);
        r.z = fsig((uv.z - mu) * rr) * ftanh(vv.z);
        r.w = fsig((uv.w - mu) * rr) * ftanh(vv.w);
        ((float4*)(out + (size_t)6 * GATE_SZ))[i] = r;
    }
}

extern "C" void kernel_launch(void* const* d_in, const int* in_sizes, int n_in,
                              void* d_out, int out_size, void* d_ws, size_t ws_size,
                              hipStream_t stream)
{
    const float* x    = (const float*)d_in[0];
    const float* ch   = (const float*)d_in[1];
    const float* m    = (const float*)d_in[2];
    const float* h    = (const float*)d_in[3];
    const float* Wx   = (const float*)d_in[4];
    const float* bx   = (const float*)d_in[5];
    const float* Wh   = (const float*)d_in[6];
    const float* bh   = (const float*)d_in[7];
    const float* w111 = (const float*)d_in[8];
    const float* b111 = (const float*)d_in[9];
    const float* lnw  = (const float*)d_in[10];
    const float* lnb  = (const float*)d_in[11];
    float* out = (float*)d_out;
    float* ws  = (float*)d_ws;

    // Scratch placement in DEAD d_out slots (ws stays within the proven
    // 4*GATE_SZ+128-float footprint):
    //   slot 0: u0 (raw r) until scores_k; then PCM (8 MB) written by cm_pcm_k,
    //           read by conv MODE 1/2, finally overwritten by tail_k (hist copy).
    //   slot 4: XH (6 MB) dead after MODE 0; slot rewritten by cm_pcm_k with c.
    //   slot 5: A7 (2.2 MB) dead after MODE 0; rewritten by cm_pcm_k (m_new).
    //   slot 6: XM (6 MB) + Ao/A111 (0.46 MB) + LN4 partials (64 KB) + LN3 sums
    //           (28 KB) — all consumed before tail_k writes h_new at the end.
    u16* XH   = (u16*)(out + (size_t)4 * GATE_SZ);
    u16* A7   = (u16*)(out + (size_t)5 * GATE_SZ);
    u16* XM   = (u16*)(out + (size_t)6 * GATE_SZ);
    u16* Ao   = XM + (size_t)BATCH * 4096 * 96;      // behind XM, same slot
    u16* A111 = Ao + (size_t)NO;
    u16* PCM  = (u16*)out;                           // slot 0 (dead after scores_k)
    float* part = (float*)(A111 + N1);               // 16384 floats, slot-6 dead zone
    float* sums = part + 16384;                      // 7168 floats, slot-6 dead zone
    float* stats = ws + WS_ST_OFF;

    pack_w_k<<<(N7 + NO + N1 + 255) / 256, 256, 0, stream>>>(Wx, Wh, w111, A7, Ao, A111, stats, sums);
    pack_xhm_k<<<512, 256, 0, stream>>>(x, h, m, XH, XM);

    // MODE 0: MT=4, MINW=3, runtime 2-deep dbuf (R0-proven 101 us config) + sums
    conv_mfma_k<96, 27, 2, 0, 4, 3><<<896, 256, 0, stream>>>(XH, XM, A7, bx, bh, nullptr, out, ws, sums);

    scores_k<<<512, 256, 0, stream>>>(out, ch, sums, stats);         // sigma(LN(u0)) inline
    recall_k<<<8192, 256, 0, stream>>>(ch, ws, part);                // softmax fused
    cm_pcm_k<<<512, 256, 0, stream>>>(out, ws, m, lnw, lnb, part, sums, PCM);

    // MODE 1: oc-split MT=2 -> 512 blocks = 2/CU; epilogue fills sums[g=6]
    conv_mfma_k<128, 27, 1, 1, 2, 4><<<512, 256, 0, stream>>>(PCM, nullptr, Ao, nullptr, bh, nullptr, out, ws, sums);
    // MODE 2: 1x1x1 conv -> v (ws slot 0)
    conv_mfma_k<128, 1, 1, 2, 4, 3><<<256, 256, 0, stream>>>(PCM, nullptr, A111, nullptr, nullptr, b111, out, ws, nullptr);

    // tail: hist copy + h_new with o-gate LN+sigmoid fused (ln3_act_k eliminated)
    tail_k<<<10240, 256, 0, stream>>>(ch, ws + (size_t)2 * GATE_SZ, ws, sums, out);
}

// Round 9
// 386.712 us; speedup vs baseline: 1.1386x; 1.0561x over previous
//
#include <hip/hip_runtime.h>
#include <hip/hip_bf16.h>
#include <math.h>

// Problem constants
#define BATCH 8
#define CIN 16
#define HID 64
#define S2 1024            // 32*32
#define SP 4096            // 4*32*32 spatial elems per channel
#define CHB 262144         // HID*SP per batch
#define TAU 5
#define GATE_SZ 2097152    // BATCH*CHB floats = one gate buffer
#define EPS 1e-5f

// ws layout (floats): [0..3*GATE_SZ) = u4,u5,u6 ; [3G) Z ; [4G) stats(128 floats).
#define WS_Z_OFF   ((size_t)3 * GATE_SZ)
#define WS_ST_OFF  ((size_t)4 * GATE_SZ)
// stats: scores[0..39] (l*8+b)

typedef unsigned short u16;
typedef __attribute__((ext_vector_type(8))) short  short8;
typedef __attribute__((ext_vector_type(8))) u16    ushort8;
typedef __attribute__((ext_vector_type(4))) float  f32x4;

#define N7 (7*27*64*96)
#define NO (27*64*128)
#define N1 (64*128)

__device__ __forceinline__ u16 f2b(float v) {
    __hip_bfloat16 h = __float2bfloat16(v);
    u16 r; __builtin_memcpy(&r, &h, 2); return r;
}

__device__ __forceinline__ float* gate_ptr(float* out, float* ws, int g) {
    return (g < 4) ? (out + (size_t)g * GATE_SZ) : (ws + (size_t)(g - 4) * GATE_SZ);
}

// fast activations: native v_exp_f32 via __expf, clamped so exp never overflows
__device__ __forceinline__ float fsig(float v) {
    v = fminf(fmaxf(v, -30.f), 30.f);
    return 1.f / (1.f + __expf(-v));
}
__device__ __forceinline__ float ftanh(float v) {
    v = fminf(fmaxf(v, -15.f), 15.f);
    const float t = __expf(-2.f * v);
    return (1.f - t) / (1.f + t);
}

// ---- weight pack: A7[g][tap][oc][96], Ao[tap][oc][128], A111[oc][128] (bf16) ----
// Also zeroes the scores-stats block (replaces a hipMemsetAsync dispatch).
__global__ __launch_bounds__(256) void pack_w_k(const float* __restrict__ Wx,
                                                const float* __restrict__ Wh,
                                                const float* __restrict__ w111,
                                                u16* __restrict__ A7, u16* __restrict__ Ao,
                                                u16* __restrict__ A111,
                                                float* __restrict__ stats)
{
    const int idx = blockIdx.x * 256 + threadIdx.x;
    if (idx < 128) stats[idx] = 0.f;
    if (idx < N7) {
        const int k = idx % 96, oc = (idx / 96) % 64, tap = (idx / (96*64)) % 27, g = idx / (96*64*27);
        float v = 0.f;
        if (k < 16)      v = Wx[((size_t)(g*64 + oc)*16 + k)      * 27 + tap];
        else if (k < 80) v = Wh[((size_t)(g*64 + oc)*64 + (k-16)) * 27 + tap];
        A7[idx] = f2b(v);
    } else if (idx < N7 + NO) {
        const int j = idx - N7;
        const int k = j % 128, oc = (j / 128) % 64, tap = j / (128*64);
        float v = (k < 64) ? Wh[((size_t)(7*64 + oc)*64 + k)      * 27 + tap]
                           : Wh[((size_t)(8*64 + oc)*64 + (k-64)) * 27 + tap];
        Ao[j] = f2b(v);
    } else if (idx < N7 + NO + N1) {
        const int j = idx - N7 - NO;
        A111[j] = f2b(w111[j]);
    }
}

// ---- input pack: XH[b][4096][96], XM[b][4096][96] (bf16, ch-minor) ----
__global__ __launch_bounds__(256) void pack_xhm_k(const float* __restrict__ x,
                                                  const float* __restrict__ h,
                                                  const float* __restrict__ m,
                                                  u16* __restrict__ XH, u16* __restrict__ XM)
{
    __shared__ float t[144][65];
    const int bi = blockIdx.x, b = bi >> 6, s0 = (bi & 63) << 6;
    for (int i = threadIdx.x; i < 144*64; i += 256) {
        const int row = i >> 6, sc = i & 63;
        float v;
        if (row < 16)      v = x[((size_t)b*16 + row)      * SP + s0 + sc];
        else if (row < 80) v = h[((size_t)b*64 + (row-16)) * SP + s0 + sc];
        else               v = m[((size_t)b*64 + (row-80)) * SP + s0 + sc];
        t[row][sc] = v;
    }
    __syncthreads();
    for (int j = threadIdx.x; j < 64*96; j += 256) {
        const int s = j / 96, ch = j % 96;
        const size_t o = ((size_t)b*4096 + s0 + s) * 96 + ch;
        XH[o] = f2b(ch < 80 ? t[ch][s] : 0.f);
        XM[o] = f2b(ch < 16 ? t[ch][s] : (ch < 80 ? t[ch + 64][s] : 0.f));
    }
}

// ---- implicit-GEMM conv via MFMA 16x16x32 bf16, runtime 2-deep pipelined taps ----
// Measured config ladder: R0 runtime-dbuf+PADK40+MT4+MINW3 = 101 us (BEST).
// Swizzle = 105 (XOR VALU > conflict cost). Compile-time tap unroll at MT4
// spills (R7: 169). MT2 at MODE0 doubles staging (R4: 112.6). Sums-epilogue
// atomics cost ~20 us of contention (R8: 121) — NO fused stats here.
// MODE 0: 7 gate convs (K=96, 27 taps, XH/XM, bias bx+bh, write)
// MODE 1: o-gate state conv (K=128, 27 taps, PCM, read-add-store onto MODE-0 g6),
//         oc-split MT=2 grid 512 -> 2 blocks/CU (R7: -8 us vs 1/CU)
// MODE 2: 1x1x1 conv (K=128, 1 tap -> weight tap 0 (R5 bug), write v to ws slot 0)
template<int KCH, int TAPS, int NR, int MODE, int MT, int MINW>
__global__ __launch_bounds__(256, MINW) void conv_mfma_k(
    const u16* __restrict__ XA, const u16* __restrict__ XB,
    const u16* __restrict__ Apack,
    const float* __restrict__ bxp, const float* __restrict__ bhp,
    const float* __restrict__ b111,
    float* __restrict__ out, float* __restrict__ ws)
{
    constexpr int YT   = NR + 2;        // y rows in tile (with halo)
    constexpr int ROWS = 4 * YT * 34;   // t * y * x(with halo)
    constexpr int PADK = 40;            // 80B rows, 16B aligned
    __shared__ __align__(16) u16 xs[ROWS * PADK];

    const int bi = blockIdx.x;
    int g = 0, b, y0, ocb = 0;
    const u16* X; const u16* Ag; float* outp;
    if (MODE == 0) {
        constexpr int YB = 32 / NR;
        g  = bi / (8 * YB);
        b  = (bi / YB) % 8;
        y0 = (bi % YB) * NR;
        X  = (g >= 3 && g <= 5) ? XB : XA;
        Ag = Apack + (size_t)g * TAPS * 64 * KCH;
        outp = gate_ptr(out, ws, g) + (size_t)b * CHB;
    } else if (MODE == 1) {
        ocb = (bi & 1) * 32;            // oc half (MT=2): grid 512 = 8b*32y*2oc
        b  = bi >> 6;
        y0 = (bi >> 1) & 31;
        X = XA; Ag = Apack;
        outp = ws + (size_t)2 * GATE_SZ + (size_t)b * CHB;
    } else {
        b = bi >> 5; y0 = bi & 31;
        X = XA; Ag = Apack;
        outp = ws + (size_t)b * CHB;
    }
    const u16* Xb = X + (size_t)b * 4096 * KCH;

    const int tid  = threadIdx.x;
    const int w    = tid >> 6;          // wave = output t-plane
    const int lane = tid & 63;
    const int xn   = lane & 15, quad = lane >> 4;

    f32x4 acc[MT][2 * NR] = {};

    for (int kc = 0; kc < KCH / 32; ++kc) {
        if (kc != 0) __syncthreads();
        // stage 32-channel slab of the (t, y-halo, x-halo) tile into LDS
        for (int cix = tid; cix < ROWS * 4; cix += 256) {
            const int r = cix >> 2, sub = cix & 3;
            const int t = r / (YT * 34), rem = r % (YT * 34);
            const int yy = rem / 34, xx = rem % 34;
            const int gy = y0 + yy - 1, gx = xx - 1;
            ushort8 v = {0, 0, 0, 0, 0, 0, 0, 0};
            if ((unsigned)gy < 32u && (unsigned)gx < 32u)
                v = *(const ushort8*)&Xb[(size_t)(t * 1024 + gy * 32 + gx) * KCH + kc * 32 + sub * 8];
            *(ushort8*)&xs[r * PADK + sub * 8] = v;
        }
        __syncthreads();

        auto load_a = [&](short8* a, int tap) {
            #pragma unroll
            for (int mt = 0; mt < MT; ++mt)
                a[mt] = *(const short8*)
                    &Ag[(size_t)(tap * 64 + ocb + mt * 16 + xn) * KCH + kc * 32 + quad * 8];
        };
        auto load_b = [&](short8* bf, int tap) {
            int kd, ky, kx;
            if (TAPS == 27) { kd = tap / 9; ky = (tap / 3) % 3; kx = tap % 3; }
            else            { kd = 1; ky = 1; kx = 1; }
            const int tin = w + kd - 1;
            #pragma unroll
            for (int nt = 0; nt < 2 * NR; ++nt) {
                const int ysub = nt >> 1, xh = nt & 1;
                bf[nt] = *(const short8*)
                    &xs[((tin * YT + ysub + ky) * 34 + xh * 16 + xn + kx) * PADK + quad * 8];
            }
        };
        auto do_mfma = [&](short8* a, short8* bf) {
            #pragma unroll
            for (int nt = 0; nt < 2 * NR; ++nt)
                #pragma unroll
                for (int mt = 0; mt < MT; ++mt)
                    acc[mt][nt] = __builtin_amdgcn_mfma_f32_16x16x32_bf16(a[mt], bf[nt], acc[mt][nt], 0, 0, 0);
        };

        if (TAPS == 27) {
            // valid taps form a contiguous range per wave (t-plane)
            const int tap_lo = (w == 0) ? 9 : 0;
            const int tap_hi = (w == 3) ? 18 : 27;
            short8 a0[MT], b0[2 * NR], a1[MT], b1[2 * NR];
            load_a(a0, tap_lo); load_b(b0, tap_lo);
            int tap = tap_lo;
            for (; tap + 2 <= tap_hi; tap += 2) {
                load_a(a1, tap + 1); load_b(b1, tap + 1);   // prefetch tap+1
                do_mfma(a0, b0);                            // compute tap
                if (tap + 2 < tap_hi) { load_a(a0, tap + 2); load_b(b0, tap + 2); }
                do_mfma(a1, b1);                            // compute tap+1
            }
            if (tap < tap_hi) do_mfma(a0, b0);              // odd tail
        } else {
            short8 a0[MT], b0[2 * NR];
            load_a(a0, 0); load_b(b0, 0);                   // 1-tap pack: weight tap 0
            do_mfma(a0, b0);
        }
    }

    // epilogue: C/D layout col=lane&15, row=quad*4+reg (R0 order, no fused stats)
    #pragma unroll
    for (int mt = 0; mt < MT; ++mt)
    #pragma unroll
    for (int nt = 0; nt < 2 * NR; ++nt) {
        const int ysub = nt >> 1, xh = nt & 1;
        const int sp = w * 1024 + (y0 + ysub) * 32 + xh * 16 + xn;
        #pragma unroll
        for (int reg = 0; reg < 4; ++reg) {
            const int oc = ocb + mt * 16 + quad * 4 + reg;
            float bias;
            if (MODE == 0)      bias = bxp[g * 64 + oc] + bhp[g * 64 + oc];
            else if (MODE == 1) bias = bhp[7 * 64 + oc] + bhp[8 * 64 + oc];
            else                bias = b111[oc];
            float* p = outp + (size_t)oc * SP + sp;
            float vv = acc[mt][nt][reg] + bias;
            if (MODE == 1) vv += *p;     // accumulate onto MODE-0 g6 output; each
            *p = vv;                     // element owned by exactly one block
        }
    }
}

// ---- LN3 stats only (gates 0..5): mu/rstd per (g,b,c) -> lnstats table ----
__global__ __launch_bounds__(256) void ln3_stats_k(float* __restrict__ out,
                                                   float* __restrict__ ws,
                                                   float* __restrict__ lnstats)
{
    const int blk = blockIdx.x;                 // g*512 + b*64 + chn
    const int g = blk >> 9;
    const float* p = gate_ptr(out, ws, g) + (size_t)(blk & 511) * SP;
    const int tid = threadIdx.x;

    float s = 0.f, s2 = 0.f;
    for (int k = tid; k < SP; k += 256) { float v = p[k]; s += v; s2 += v * v; }
    #pragma unroll
    for (int off = 32; off > 0; off >>= 1) { s += __shfl_down(s, off); s2 += __shfl_down(s2, off); }
    __shared__ float rs[4], rs2[4];
    if ((tid & 63) == 0) { rs[tid >> 6] = s; rs2[tid >> 6] = s2; }
    __syncthreads();
    if (tid == 0) {
        float S  = rs[0] + rs[1] + rs[2] + rs[3];
        float Sq = rs2[0] + rs2[1] + rs2[2] + rs2[3];
        float mu  = S * (1.f / SP);
        float var = Sq * (1.f / SP) - mu * mu;
        lnstats[2 * blk]     = mu;
        lnstats[2 * blk + 1] = rsqrtf(var + EPS);
    }
}

// ---- LayerNorm + activation in place (gate 6 / o-gate only) ----
__global__ __launch_bounds__(256) void ln3_act_k(float* __restrict__ out,
                                                 float* __restrict__ ws, int gate0)
{
    const int blk = blockIdx.x;
    const int g = gate0 + (blk >> 9);
    float* p = gate_ptr(out, ws, g) + (size_t)(blk & 511) * SP;
    const int tid = threadIdx.x;

    float s = 0.f, s2 = 0.f;
    for (int k = tid; k < SP; k += 256) { float v = p[k]; s += v; s2 += v * v; }
    #pragma unroll
    for (int off = 32; off > 0; off >>= 1) { s += __shfl_down(s, off); s2 += __shfl_down(s2, off); }
    __shared__ float rs[4], rs2[4], stat[2];
    if ((tid & 63) == 0) { rs[tid >> 6] = s; rs2[tid >> 6] = s2; }
    __syncthreads();
    if (tid == 0) {
        float S  = rs[0] + rs[1] + rs[2] + rs[3];
        float Sq = rs2[0] + rs2[1] + rs2[2] + rs2[3];
        float mu  = S * (1.f / SP);
        float var = Sq * (1.f / SP) - mu * mu;
        stat[0] = mu; stat[1] = rsqrtf(var + EPS);
    }
    __syncthreads();
    const float mu = stat[0], r = stat[1];
    for (int k = tid; k < SP; k += 256)
        p[k] = fsig((p[k] - mu) * r);           // gate 6 is sigmoid
}

// ---- attention scores: sigma(LN(u0)) applied on the fly; one r-read, 5 dots ----
__global__ __launch_bounds__(256) void scores_k(const float* __restrict__ u0,
                                                const float* __restrict__ chist,
                                                const float* __restrict__ lnstats,
                                                float* __restrict__ stats)
{
    const int blk = blockIdx.x;            // 512 = 8 b * 64 chn (chunk == channel)
    const int b = blk >> 6, chn = blk & 63;
    const float mu = lnstats[2 * (b * 64 + chn)];
    const float rr = lnstats[2 * (b * 64 + chn) + 1];
    const float* rp = u0 + (size_t)b * CHB;
    const int lo = chn * SP;
    float s[TAU] = {};
    for (int k = lo + threadIdx.x; k < lo + SP; k += 256) {
        const float rv = fsig((rp[k] - mu) * rr);
        #pragma unroll
        for (int l = 0; l < TAU; ++l) s[l] += rv * chist[(size_t)(l * BATCH + b) * CHB + k];
    }
    __shared__ float rsh[TAU][4];
    #pragma unroll
    for (int l = 0; l < TAU; ++l) {
        float v = s[l];
        #pragma unroll
        for (int off = 32; off > 0; off >>= 1) v += __shfl_down(v, off);
        if ((threadIdx.x & 63) == 0) rsh[l][threadIdx.x >> 6] = v;
    }
    __syncthreads();
    if (threadIdx.x < TAU) {
        const int l = threadIdx.x;
        atomicAdd(&stats[l * 8 + b],
                  (rsh[l][0] + rsh[l][1] + rsh[l][2] + rsh[l][3]) * (1.f / 64.f));
    }
}

// ---- z = chist[4,b] + sum_l attn[b,l]*chist[l,b]; softmax fused; per-block partials ----
__global__ __launch_bounds__(256) void recall_k(const float* __restrict__ chist,
                                                float* __restrict__ ws,
                                                float* __restrict__ part)
{
    const float* stats = ws + WS_ST_OFF;
    const int blk = blockIdx.x;
    const int b = blk >> 10;
    const int idx = (blk & 1023) * 256 + threadIdx.x;

    // softmax over dim 0 (batch) of scores[l*8+b], per l — 5 threads, broadcast via LDS
    __shared__ float attn[TAU];
    if (threadIdx.x < TAU) {
        const int l = threadIdx.x;
        float mx = -1e30f;
        for (int bb = 0; bb < BATCH; ++bb) mx = fmaxf(mx, stats[l * 8 + bb]);
        float sum = 0.f, e = 0.f;
        for (int bb = 0; bb < BATCH; ++bb) {
            float t = __expf(stats[l * 8 + bb] - mx);
            sum += t;
            if (bb == b) e = t;
        }
        attn[l] = e / sum;
    }
    __syncthreads();
    const float a0 = attn[0], a1 = attn[1], a2 = attn[2], a3 = attn[3], a4 = attn[4];

    const size_t e = (size_t)b * CHB + idx;
    const size_t LB = (size_t)BATCH * CHB;
    float z = chist[4 * LB + e] * (1.f + a4)
            + a0 * chist[0 * LB + e] + a1 * chist[1 * LB + e]
            + a2 * chist[2 * LB + e] + a3 * chist[3 * LB + e];
    ws[WS_Z_OFF + e] = z;

    float s = z, s2 = z * z;
    #pragma unroll
    for (int off = 32; off > 0; off >>= 1) { s += __shfl_down(s, off); s2 += __shfl_down(s2, off); }
    __shared__ float rs[4], rs2[4];
    if ((threadIdx.x & 63) == 0) { rs[threadIdx.x >> 6] = s; rs2[threadIdx.x >> 6] = s2; }
    __syncthreads();
    if (threadIdx.x == 0) {
        part[blk]        = rs[0] + rs[1] + rs[2] + rs[3];
        part[8192 + blk] = rs2[0] + rs2[1] + rs2[2] + rs2[3];
    }
}

// ---- fused: LN4 stats + LN3+act of gates 1..5 on the fly + c,m_new + PCM pack ----
__global__ __launch_bounds__(256) void cm_pcm_k(float* __restrict__ out, float* __restrict__ ws,
                                                const float* __restrict__ m,
                                                const float* __restrict__ lnw,
                                                const float* __restrict__ lnb,
                                                const float* __restrict__ part,
                                                const float* __restrict__ lnstats,
                                                u16* __restrict__ PCM)
{
    __shared__ __align__(16) u16 tl[64][136];   // [sp][128 ch + pad], 16B-aligned rows
    __shared__ float lst[5][64][2];             // LN3 stats for gates 1..5, this batch
    const int bi = blockIdx.x;
    const int b = bi >> 6;
    const int s0 = (bi & 63) << 6;

    // stage LN3 stats (gates 1..5) + re-reduce the 1024 LN4 partials for this batch
    for (int j = threadIdx.x; j < 5 * 64; j += 256) {
        const int gg = j >> 6, chn = j & 63;
        lst[gg][chn][0] = lnstats[2 * ((gg + 1) * 512 + b * 64 + chn)];
        lst[gg][chn][1] = lnstats[2 * ((gg + 1) * 512 + b * 64 + chn) + 1];
    }
    float s = 0.f, s2 = 0.f;
    for (int j = threadIdx.x; j < 1024; j += 256) {
        s  += part[b * 1024 + j];
        s2 += part[8192 + b * 1024 + j];
    }
    #pragma unroll
    for (int off = 32; off > 0; off >>= 1) { s += __shfl_down(s, off); s2 += __shfl_down(s2, off); }
    __shared__ float rs[4], rs2[4], st[2];
    if ((threadIdx.x & 63) == 0) { rs[threadIdx.x >> 6] = s; rs2[threadIdx.x >> 6] = s2; }
    __syncthreads();
    if (threadIdx.x == 0) {
        float S  = rs[0] + rs[1] + rs[2] + rs[3];
        float Sq = rs2[0] + rs2[1] + rs2[2] + rs2[3];
        float mu  = S * (1.f / CHB);
        float var = Sq * (1.f / CHB) - mu * mu;
        st[0] = mu; st[1] = rsqrtf(var + EPS);
    }
    __syncthreads();
    const float mu = st[0], rstd = st[1];

    for (int i = threadIdx.x; i < 1024; i += 256) {       // 64ch x 16 float4
        const int chn = i >> 4;
        const int sp4 = (i & 15) << 2;
        const size_t e = (size_t)b * CHB + (size_t)chn * SP + s0 + sp4;
        const size_t le = (size_t)chn * SP + s0 + sp4;
        float4 z  = *(const float4*)&ws[WS_Z_OFF + e];
        float4 u1 = *(const float4*)&gate_ptr(out, ws, 1)[e];
        float4 u2 = *(const float4*)&gate_ptr(out, ws, 2)[e];
        float4 u3 = *(const float4*)&gate_ptr(out, ws, 3)[e];
        float4 u4 = *(const float4*)&gate_ptr(out, ws, 4)[e];
        float4 u5 = *(const float4*)&gate_ptr(out, ws, 5)[e];
        float4 mm = *(const float4*)&m[e];
        float4 lw = *(const float4*)&lnw[le];
        float4 lb = *(const float4*)&lnb[le];
        const float m1 = lst[0][chn][0], r1 = lst[0][chn][1];
        const float m2 = lst[1][chn][0], r2 = lst[1][chn][1];
        const float m3 = lst[2][chn][0], r3 = lst[2][chn][1];
        const float m4 = lst[3][chn][0], r4 = lst[3][chn][1];
        const float m5 = lst[4][chn][0], r5 = lst[4][chn][1];
        float4 c, mn;
        {
            const float uu1[4] = {u1.x, u1.y, u1.z, u1.w};
            const float uu2[4] = {u2.x, u2.y, u2.z, u2.w};
            const float uu3[4] = {u3.x, u3.y, u3.z, u3.w};
            const float uu4[4] = {u4.x, u4.y, u4.z, u4.w};
            const float uu5[4] = {u5.x, u5.y, u5.z, u5.w};
            const float zz[4]  = {z.x, z.y, z.z, z.w};
            const float mmv[4] = {mm.x, mm.y, mm.z, mm.w};
            const float lwv[4] = {lw.x, lw.y, lw.z, lw.w};
            const float lbv[4] = {lb.x, lb.y, lb.z, lb.w};
            float cv[4], mv[4];
            #pragma unroll
            for (int k = 0; k < 4; ++k) {
                const float gi = fsig ((uu1[k] - m1) * r1);
                const float gg = ftanh((uu2[k] - m2) * r2);
                const float ip = fsig ((uu3[k] - m3) * r3);
                const float gp = ftanh((uu4[k] - m4) * r4);
                const float fp = fsig ((uu5[k] - m5) * r5);
                cv[k] = gi * gg + (zz[k] - mu) * rstd * lwv[k] + lbv[k];
                mv[k] = ip * gp + fp * mmv[k];
                tl[sp4 + k][chn]      = f2b(cv[k]);
                tl[sp4 + k][64 + chn] = f2b(mv[k]);
            }
            c.x = cv[0]; c.y = cv[1]; c.z = cv[2]; c.w = cv[3];
            mn.x = mv[0]; mn.y = mv[1]; mn.z = mv[2]; mn.w = mv[3];
        }
        *(float4*)&out[(size_t)4 * GATE_SZ + e] = c;
        *(float4*)&out[(size_t)5 * GATE_SZ + e] = mn;
    }
    __syncthreads();
    for (int j = threadIdx.x; j < 1024; j += 256) {       // 64 s x 16 ushort8
        const int sidx = j >> 4, c8 = (j & 15) << 3;
        ushort8 v = *(const ushort8*)&tl[sidx][c8];
        *(ushort8*)&PCM[((size_t)b * 4096 + s0 + sidx) * 128 + c8] = v;
    }
}

// ---- merged tail: c_history_new[0:4] = c_history[1:5]  AND  h_new = o * tanh(v) ----
__global__ __launch_bounds__(256) void tail_k(const float* __restrict__ chist,
                                              const float* __restrict__ o,
                                              const float* __restrict__ v,
                                              float* __restrict__ out)
{
    const int bi = blockIdx.x;
    if (bi < 8192) {
        const size_t i = (size_t)bi * 256 + threadIdx.x;
        ((float4*)out)[i] = ((const float4*)(chist + GATE_SZ))[i];
    } else {
        const size_t i = (size_t)(bi - 8192) * 256 + threadIdx.x;
        float4 ov = ((const float4*)o)[i], vv = ((const float4*)v)[i];
        float4 r;
        r.x = ov.x * ftanh(vv.x); r.y = ov.y * ftanh(vv.y);
        r.z = ov.z * ftanh(vv.z); r.w = ov.w * ftanh(vv.w);
        ((float4*)(out + (size_t)6 * GATE_SZ))[i] = r;
    }
}

extern "C" void kernel_launch(void* const* d_in, const int* in_sizes, int n_in,
                              void* d_out, int out_size, void* d_ws, size_t ws_size,
                              hipStream_t stream)
{
    const float* x    = (const float*)d_in[0];
    const float* ch   = (const float*)d_in[1];
    const float* m    = (const float*)d_in[2];
    const float* h    = (const float*)d_in[3];
    const float* Wx   = (const float*)d_in[4];
    const float* bx   = (const float*)d_in[5];
    const float* Wh   = (const float*)d_in[6];
    const float* bh   = (const float*)d_in[7];
    const float* w111 = (const float*)d_in[8];
    const float* b111 = (const float*)d_in[9];
    const float* lnw  = (const float*)d_in[10];
    const float* lnb  = (const float*)d_in[11];
    float* out = (float*)d_out;
    float* ws  = (float*)d_ws;

    // Scratch placement in DEAD d_out slots (ws stays within the proven
    // 4*GATE_SZ+128-float footprint):
    //   slot 0: u0 (raw r) until scores_k; then PCM (8 MB) written by cm_pcm_k,
    //           read by conv MODE 1/2, finally overwritten by tail_k (hist copy).
    //   slot 4: XH (6 MB) dead after MODE 0; slot rewritten by cm_pcm_k with c.
    //   slot 5: A7 (2.2 MB) dead after MODE 0; rewritten by cm_pcm_k (m_new).
    //   slot 6: XM (6 MB) + Ao/A111 (0.46 MB) + LN4 partials (64 KB) + LN3 stats
    //           (24 KB) — all consumed before tail_k writes h_new at the end.
    u16* XH   = (u16*)(out + (size_t)4 * GATE_SZ);
    u16* A7   = (u16*)(out + (size_t)5 * GATE_SZ);
    u16* XM   = (u16*)(out + (size_t)6 * GATE_SZ);
    u16* Ao   = XM + (size_t)BATCH * 4096 * 96;      // behind XM, same slot
    u16* A111 = Ao + (size_t)NO;
    u16* PCM  = (u16*)out;                           // slot 0 (dead after scores_k)
    float* part    = (float*)(A111 + N1);            // 16384 floats, slot-6 dead zone
    float* lnstats = part + 16384;                   // 6144 floats, slot-6 dead zone
    float* stats   = ws + WS_ST_OFF;

    pack_w_k<<<(N7 + NO + N1 + 255) / 256, 256, 0, stream>>>(Wx, Wh, w111, A7, Ao, A111, stats);
    pack_xhm_k<<<512, 256, 0, stream>>>(x, h, m, XH, XM);

    // MODE 0: R0-proven config — MT=4, MINW=3, runtime 2-deep dbuf, no fused stats
    conv_mfma_k<96, 27, 2, 0, 4, 3><<<896, 256, 0, stream>>>(XH, XM, A7, bx, bh, nullptr, out, ws);
    ln3_stats_k<<<3072, 256, 0, stream>>>(out, ws, lnstats);         // gates 0..5 stats only

    scores_k<<<512, 256, 0, stream>>>(out, ch, lnstats, stats);      // sigma(LN(u0)) inline
    recall_k<<<8192, 256, 0, stream>>>(ch, ws, part);                // softmax fused
    cm_pcm_k<<<512, 256, 0, stream>>>(out, ws, m, lnw, lnb, part, lnstats, PCM);

    // MODE 1: oc-split MT=2 -> 512 blocks = 2/CU (R7-proven)
    conv_mfma_k<128, 27, 1, 1, 2, 4><<<512, 256, 0, stream>>>(PCM, nullptr, Ao, nullptr, bh, nullptr, out, ws);
    ln3_act_k<<<512, 256, 0, stream>>>(out, ws, 6);                  // gate 6 (o)
    conv_mfma_k<128, 1, 1, 2, 4, 3><<<256, 256, 0, stream>>>(PCM, nullptr, A111, nullptr, nullptr, b111, out, ws);

    tail_k<<<10240, 256, 0, stream>>>(ch, ws + (size_t)2 * GATE_SZ, ws, out);
}

// Round 10
// 365.436 us; speedup vs baseline: 1.2049x; 1.0582x over previous
//
#include <hip/hip_runtime.h>
#include <hip/hip_bf16.h>
#include <math.h>

// Problem constants
#define BATCH 8
#define CIN 16
#define HID 64
#define S2 1024            // 32*32
#define SP 4096            // 4*32*32 spatial elems per channel
#define CHB 262144         // HID*SP per batch
#define TAU 5
#define GATE_SZ 2097152    // BATCH*CHB floats = one gate buffer
#define EPS 1e-5f

// ws layout (floats): [0..3*GATE_SZ) = u4,u5,u6 ; [3G) Z ; [4G) stats(128 floats).
// lnstats for g6 (2048 floats) reuses the HEAD of the Z region (dead after cm_pcm,
// written by lnred_B after MODE-1, read only by tail_k which never writes ws).
#define WS_Z_OFF   ((size_t)3 * GATE_SZ)
#define WS_ST_OFF  ((size_t)4 * GATE_SZ)
// stats: scores[0..39] (l*8+b)

typedef unsigned short u16;
typedef __attribute__((ext_vector_type(8))) short  short8;
typedef __attribute__((ext_vector_type(8))) u16    ushort8;
typedef __attribute__((ext_vector_type(4))) float  f32x4;

#define N7 (7*27*64*96)
#define NO (27*64*128)
#define N1 (64*128)
// part2 layout: g<6 -> idx = (g*512 + b*64 + oc)*16 + y0/2   (16 y-blocks)
//               g=6 -> idx = 49152 + (b*64 + oc)*32 + y0     (32 y-blocks)
#define NP2 65536

__device__ __forceinline__ u16 f2b(float v) {
    __hip_bfloat16 h = __float2bfloat16(v);
    u16 r; __builtin_memcpy(&r, &h, 2); return r;
}

__device__ __forceinline__ float* gate_ptr(float* out, float* ws, int g) {
    return (g < 4) ? (out + (size_t)g * GATE_SZ) : (ws + (size_t)(g - 4) * GATE_SZ);
}

// fast activations: native v_exp_f32 via __expf, clamped so exp never overflows
__device__ __forceinline__ float fsig(float v) {
    v = fminf(fmaxf(v, -30.f), 30.f);
    return 1.f / (1.f + __expf(-v));
}
__device__ __forceinline__ float ftanh(float v) {
    v = fminf(fmaxf(v, -15.f), 15.f);
    const float t = __expf(-2.f * v);
    return (1.f - t) / (1.f + t);
}

// ---- weight pack: A7[g][tap][oc][96], Ao[tap][oc][128], A111[oc][128] (bf16) ----
__global__ __launch_bounds__(256) void pack_w_k(const float* __restrict__ Wx,
                                                const float* __restrict__ Wh,
                                                const float* __restrict__ w111,
                                                u16* __restrict__ A7, u16* __restrict__ Ao,
                                                u16* __restrict__ A111,
                                                float* __restrict__ stats)
{
    const int idx = blockIdx.x * 256 + threadIdx.x;
    if (idx < 128) stats[idx] = 0.f;
    if (idx < N7) {
        const int k = idx % 96, oc = (idx / 96) % 64, tap = (idx / (96*64)) % 27, g = idx / (96*64*27);
        float v = 0.f;
        if (k < 16)      v = Wx[((size_t)(g*64 + oc)*16 + k)      * 27 + tap];
        else if (k < 80) v = Wh[((size_t)(g*64 + oc)*64 + (k-16)) * 27 + tap];
        A7[idx] = f2b(v);
    } else if (idx < N7 + NO) {
        const int j = idx - N7;
        const int k = j % 128, oc = (j / 128) % 64, tap = j / (128*64);
        float v = (k < 64) ? Wh[((size_t)(7*64 + oc)*64 + k)      * 27 + tap]
                           : Wh[((size_t)(8*64 + oc)*64 + (k-64)) * 27 + tap];
        Ao[j] = f2b(v);
    } else if (idx < N7 + NO + N1) {
        const int j = idx - N7 - NO;
        A111[j] = f2b(w111[j]);
    }
}

// ---- input pack: XH[b][4096][96], XM[b][4096][96] (bf16, ch-minor) ----
__global__ __launch_bounds__(256) void pack_xhm_k(const float* __restrict__ x,
                                                  const float* __restrict__ h,
                                                  const float* __restrict__ m,
                                                  u16* __restrict__ XH, u16* __restrict__ XM)
{
    __shared__ float t[144][65];
    const int bi = blockIdx.x, b = bi >> 6, s0 = (bi & 63) << 6;
    for (int i = threadIdx.x; i < 144*64; i += 256) {
        const int row = i >> 6, sc = i & 63;
        float v;
        if (row < 16)      v = x[((size_t)b*16 + row)      * SP + s0 + sc];
        else if (row < 80) v = h[((size_t)b*64 + (row-16)) * SP + s0 + sc];
        else               v = m[((size_t)b*64 + (row-80)) * SP + s0 + sc];
        t[row][sc] = v;
    }
    __syncthreads();
    for (int j = threadIdx.x; j < 64*96; j += 256) {
        const int s = j / 96, ch = j % 96;
        const size_t o = ((size_t)b*4096 + s0 + s) * 96 + ch;
        XH[o] = f2b(ch < 80 ? t[ch][s] : 0.f);
        XM[o] = f2b(ch < 16 ? t[ch][s] : (ch < 80 ? t[ch + 64][s] : 0.f));
    }
}

// ---- implicit-GEMM conv via MFMA 16x16x32 bf16, runtime 2-deep pipelined taps ----
// R0-proven core (101 us): PADK=40, MT=4, MINW=3, runtime 2-deep dbuf tap loop.
// R8 lesson: fused-stats ATOMICS cost ~20 us of same-address contention. This
// version writes per-block partials to DISTINCT addresses (shfl + 2KB LDS
// cross-wave reduce + 64 plain coalesced stores) — no atomics.
// MODE 0: 7 gate convs; partials for g<6 -> part2.
// MODE 1: o-gate conv, oc-split MT=2 grid 512 = 2/CU, read-add-store; final u6
//         partials -> part2 g6 slot.
// MODE 2: 1x1x1 conv (weight tap 0 — R5 bug), write v to ws slot 0, no stats.
template<int KCH, int TAPS, int NR, int MODE, int MT, int MINW>
__global__ __launch_bounds__(256, MINW) void conv_mfma_k(
    const u16* __restrict__ XA, const u16* __restrict__ XB,
    const u16* __restrict__ Apack,
    const float* __restrict__ bxp, const float* __restrict__ bhp,
    const float* __restrict__ b111,
    float* __restrict__ out, float* __restrict__ ws,
    float* __restrict__ p2s, float* __restrict__ p2s2)
{
    constexpr int YT   = NR + 2;        // y rows in tile (with halo)
    constexpr int ROWS = 4 * YT * 34;   // t * y * x(with halo)
    constexpr int PADK = 40;            // 80B rows, 16B aligned
    __shared__ __align__(16) u16 xs[ROWS * PADK];
    __shared__ float red[4][MT * 16][2];

    const int bi = blockIdx.x;
    int g = 0, b, y0, ocb = 0;
    const u16* X; const u16* Ag; float* outp;
    if (MODE == 0) {
        constexpr int YB = 32 / NR;
        g  = bi / (8 * YB);
        b  = (bi / YB) % 8;
        y0 = (bi % YB) * NR;
        X  = (g >= 3 && g <= 5) ? XB : XA;
        Ag = Apack + (size_t)g * TAPS * 64 * KCH;
        outp = gate_ptr(out, ws, g) + (size_t)b * CHB;
    } else if (MODE == 1) {
        ocb = (bi & 1) * 32;            // oc half (MT=2): grid 512 = 8b*32y*2oc
        b  = bi >> 6;
        y0 = (bi >> 1) & 31;
        X = XA; Ag = Apack;
        outp = ws + (size_t)2 * GATE_SZ + (size_t)b * CHB;
    } else {
        b = bi >> 5; y0 = bi & 31;
        X = XA; Ag = Apack;
        outp = ws + (size_t)b * CHB;
    }
    const u16* Xb = X + (size_t)b * 4096 * KCH;

    const int tid  = threadIdx.x;
    const int w    = tid >> 6;          // wave = output t-plane
    const int lane = tid & 63;
    const int xn   = lane & 15, quad = lane >> 4;

    f32x4 acc[MT][2 * NR] = {};

    for (int kc = 0; kc < KCH / 32; ++kc) {
        if (kc != 0) __syncthreads();
        // stage 32-channel slab of the (t, y-halo, x-halo) tile into LDS
        for (int cix = tid; cix < ROWS * 4; cix += 256) {
            const int r = cix >> 2, sub = cix & 3;
            const int t = r / (YT * 34), rem = r % (YT * 34);
            const int yy = rem / 34, xx = rem % 34;
            const int gy = y0 + yy - 1, gx = xx - 1;
            ushort8 v = {0, 0, 0, 0, 0, 0, 0, 0};
            if ((unsigned)gy < 32u && (unsigned)gx < 32u)
                v = *(const ushort8*)&Xb[(size_t)(t * 1024 + gy * 32 + gx) * KCH + kc * 32 + sub * 8];
            *(ushort8*)&xs[r * PADK + sub * 8] = v;
        }
        __syncthreads();

        auto load_a = [&](short8* a, int tap) {
            #pragma unroll
            for (int mt = 0; mt < MT; ++mt)
                a[mt] = *(const short8*)
                    &Ag[(size_t)(tap * 64 + ocb + mt * 16 + xn) * KCH + kc * 32 + quad * 8];
        };
        auto load_b = [&](short8* bf, int tap) {
            int kd, ky, kx;
            if (TAPS == 27) { kd = tap / 9; ky = (tap / 3) % 3; kx = tap % 3; }
            else            { kd = 1; ky = 1; kx = 1; }
            const int tin = w + kd - 1;
            #pragma unroll
            for (int nt = 0; nt < 2 * NR; ++nt) {
                const int ysub = nt >> 1, xh = nt & 1;
                bf[nt] = *(const short8*)
                    &xs[((tin * YT + ysub + ky) * 34 + xh * 16 + xn + kx) * PADK + quad * 8];
            }
        };
        auto do_mfma = [&](short8* a, short8* bf) {
            #pragma unroll
            for (int nt = 0; nt < 2 * NR; ++nt)
                #pragma unroll
                for (int mt = 0; mt < MT; ++mt)
                    acc[mt][nt] = __builtin_amdgcn_mfma_f32_16x16x32_bf16(a[mt], bf[nt], acc[mt][nt], 0, 0, 0);
        };

        if (TAPS == 27) {
            // valid taps form a contiguous range per wave (t-plane)
            const int tap_lo = (w == 0) ? 9 : 0;
            const int tap_hi = (w == 3) ? 18 : 27;
            short8 a0[MT], b0[2 * NR], a1[MT], b1[2 * NR];
            load_a(a0, tap_lo); load_b(b0, tap_lo);
            int tap = tap_lo;
            for (; tap + 2 <= tap_hi; tap += 2) {
                load_a(a1, tap + 1); load_b(b1, tap + 1);   // prefetch tap+1
                do_mfma(a0, b0);                            // compute tap
                if (tap + 2 < tap_hi) { load_a(a0, tap + 2); load_b(b0, tap + 2); }
                do_mfma(a1, b1);                            // compute tap+1
            }
            if (tap < tap_hi) do_mfma(a0, b0);              // odd tail
        } else {
            short8 a0[MT], b0[2 * NR];
            load_a(a0, 0); load_b(b0, 0);                   // 1-tap pack: weight tap 0
            do_mfma(a0, b0);
        }
    }

    // epilogue: C/D layout col=lane&15, row=quad*4+reg (R0 store order) with
    // per-(mt,reg) LN3 partial accumulation of the FINAL value (incl. MODE-1 add).
    const bool do_stats = (MODE == 1) || (MODE == 0 && g < 6);   // block-uniform
    #pragma unroll
    for (int mt = 0; mt < MT; ++mt) {
        float sA[4] = {}, s2A[4] = {};
        #pragma unroll
        for (int nt = 0; nt < 2 * NR; ++nt) {
            const int ysub = nt >> 1, xh = nt & 1;
            const int sp = w * 1024 + (y0 + ysub) * 32 + xh * 16 + xn;
            #pragma unroll
            for (int reg = 0; reg < 4; ++reg) {
                const int oc = ocb + mt * 16 + quad * 4 + reg;
                float bias;
                if (MODE == 0)      bias = bxp[g * 64 + oc] + bhp[g * 64 + oc];
                else if (MODE == 1) bias = bhp[7 * 64 + oc] + bhp[8 * 64 + oc];
                else                bias = b111[oc];
                float* p = outp + (size_t)oc * SP + sp;
                float vv = acc[mt][nt][reg] + bias;
                if (MODE == 1) vv += *p;     // accumulate onto MODE-0 g6 output
                *p = vv;                     // each element owned by exactly one block
                if (MODE <= 1) { sA[reg] += vv; s2A[reg] += vv * vv; }
            }
        }
        if (MODE <= 1 && do_stats) {
            #pragma unroll
            for (int reg = 0; reg < 4; ++reg) {
                float s = sA[reg], s2 = s2A[reg];
                #pragma unroll
                for (int off = 8; off > 0; off >>= 1) {
                    s  += __shfl_xor(s, off);   // reduce within the 16-lane xn group
                    s2 += __shfl_xor(s2, off);
                }
                if (xn == 0) {
                    red[w][mt * 16 + quad * 4 + reg][0] = s;
                    red[w][mt * 16 + quad * 4 + reg][1] = s2;
                }
            }
        }
    }
    if (MODE <= 1 && do_stats) {
        __syncthreads();                     // block-uniform condition -> safe
        if (tid < MT * 16) {
            const float s  = red[0][tid][0] + red[1][tid][0] + red[2][tid][0] + red[3][tid][0];
            const float s2 = red[0][tid][1] + red[1][tid][1] + red[2][tid][1] + red[3][tid][1];
            const int oc = ocb + tid;
            const int idx = (MODE == 0) ? ((g * 512 + b * 64 + oc) * 16 + (y0 >> 1))
                                        : (49152 + (b * 64 + oc) * 32 + y0);
            p2s[idx]  = s;                   // distinct address per block — NO atomics
            p2s2[idx] = s2;
        }
    }
}

// ---- reduce per-block LN3 partials -> mu/rstd table ----
// entries e in [e0,e1): g = e>>9, b*64+chn = e&511. Writes lnstats[2*(e-ebase)].
__global__ __launch_bounds__(256) void lnred_k(const float* __restrict__ p2s,
                                               const float* __restrict__ p2s2,
                                               float* __restrict__ lnstats,
                                               int e0, int e1, int ebase)
{
    const int e = e0 + blockIdx.x * 256 + threadIdx.x;
    if (e >= e1) return;
    const int g = e >> 9, bc = e & 511;
    float s = 0.f, s2 = 0.f;
    if (g < 6) {
        const int base = e * 16;
        #pragma unroll
        for (int i = 0; i < 16; ++i) { s += p2s[base + i]; s2 += p2s2[base + i]; }
    } else {
        const int base = 49152 + bc * 32;
        #pragma unroll
        for (int i = 0; i < 32; ++i) { s += p2s[base + i]; s2 += p2s2[base + i]; }
    }
    const float mu = s * (1.f / SP);
    const float var = s2 * (1.f / SP) - mu * mu;
    lnstats[2 * (e - ebase)]     = mu;
    lnstats[2 * (e - ebase) + 1] = rsqrtf(var + EPS);
}

// ---- attention scores: sigma(LN(u0)) on the fly, float4 streams ----
__global__ __launch_bounds__(256) void scores_k(const float* __restrict__ u0,
                                                const float* __restrict__ chist,
                                                const float* __restrict__ lnstats,
                                                float* __restrict__ stats)
{
    const int blk = blockIdx.x;            // 512 = 8 b * 64 chn
    const int b = blk >> 6, chn = blk & 63;
    const float mu = lnstats[2 * (b * 64 + chn)];
    const float rr = lnstats[2 * (b * 64 + chn) + 1];
    const float4* rp4 = (const float4*)(u0 + (size_t)b * CHB);
    const int lo4 = chn * (SP / 4);
    float s[TAU] = {};
    for (int k = lo4 + threadIdx.x; k < lo4 + SP / 4; k += 256) {
        const float4 rv = rp4[k];
        const float r0 = fsig((rv.x - mu) * rr), r1 = fsig((rv.y - mu) * rr);
        const float r2 = fsig((rv.z - mu) * rr), r3 = fsig((rv.w - mu) * rr);
        #pragma unroll
        for (int l = 0; l < TAU; ++l) {
            const float4 c4 = ((const float4*)(chist + (size_t)(l * BATCH + b) * CHB))[k];
            s[l] += r0 * c4.x + r1 * c4.y + r2 * c4.z + r3 * c4.w;
        }
    }
    __shared__ float rsh[TAU][4];
    #pragma unroll
    for (int l = 0; l < TAU; ++l) {
        float v = s[l];
        #pragma unroll
        for (int off = 32; off > 0; off >>= 1) v += __shfl_down(v, off);
        if ((threadIdx.x & 63) == 0) rsh[l][threadIdx.x >> 6] = v;
    }
    __syncthreads();
    if (threadIdx.x < TAU) {
        const int l = threadIdx.x;
        atomicAdd(&stats[l * 8 + b],
                  (rsh[l][0] + rsh[l][1] + rsh[l][2] + rsh[l][3]) * (1.f / 64.f));
    }
}

// ---- z = chist[4,b] + sum_l attn[b,l]*chist[l,b]; softmax fused; float4 ----
// grid 2048 = 8 b * 256 chunks; per-block LN4 partials -> part[blk], part[2048+blk]
__global__ __launch_bounds__(256) void recall_k(const float* __restrict__ chist,
                                                float* __restrict__ ws,
                                                float* __restrict__ part)
{
    const float* stats = ws + WS_ST_OFF;
    const int blk = blockIdx.x;
    const int b = blk >> 8;
    const int i4 = (blk & 255) * 256 + threadIdx.x;   // float4 index within batch

    __shared__ float attn[TAU];
    if (threadIdx.x < TAU) {
        const int l = threadIdx.x;
        float mx = -1e30f;
        for (int bb = 0; bb < BATCH; ++bb) mx = fmaxf(mx, stats[l * 8 + bb]);
        float sum = 0.f, e = 0.f;
        for (int bb = 0; bb < BATCH; ++bb) {
            float t = __expf(stats[l * 8 + bb] - mx);
            sum += t;
            if (bb == b) e = t;
        }
        attn[l] = e / sum;
    }
    __syncthreads();
    const float a0 = attn[0], a1 = attn[1], a2 = attn[2], a3 = attn[3], a4 = attn[4];

    const size_t e4  = (size_t)b * (CHB / 4) + i4;
    const size_t LB4 = (size_t)BATCH * (CHB / 4);
    const float4* c4 = (const float4*)chist;
    const float4 h4 = c4[4 * LB4 + e4];
    const float4 v0 = c4[0 * LB4 + e4], v1 = c4[1 * LB4 + e4];
    const float4 v2 = c4[2 * LB4 + e4], v3 = c4[3 * LB4 + e4];
    float4 z;
    z.x = h4.x * (1.f + a4) + a0 * v0.x + a1 * v1.x + a2 * v2.x + a3 * v3.x;
    z.y = h4.y * (1.f + a4) + a0 * v0.y + a1 * v1.y + a2 * v2.y + a3 * v3.y;
    z.z = h4.z * (1.f + a4) + a0 * v0.z + a1 * v1.z + a2 * v2.z + a3 * v3.z;
    z.w = h4.w * (1.f + a4) + a0 * v0.w + a1 * v1.w + a2 * v2.w + a3 * v3.w;
    ((float4*)(ws + WS_Z_OFF))[e4] = z;

    float s = z.x + z.y + z.z + z.w;
    float s2 = z.x * z.x + z.y * z.y + z.z * z.z + z.w * z.w;
    #pragma unroll
    for (int off = 32; off > 0; off >>= 1) { s += __shfl_down(s, off); s2 += __shfl_down(s2, off); }
    __shared__ float rs[4], rs2[4];
    if ((threadIdx.x & 63) == 0) { rs[threadIdx.x >> 6] = s; rs2[threadIdx.x >> 6] = s2; }
    __syncthreads();
    if (threadIdx.x == 0) {
        part[blk]        = rs[0] + rs[1] + rs[2] + rs[3];
        part[2048 + blk] = rs2[0] + rs2[1] + rs2[2] + rs2[3];
    }
}

// ---- fused: LN4 stats + LN3+act of gates 1..5 on the fly + c,m_new + PCM pack ----
__global__ __launch_bounds__(256) void cm_pcm_k(float* __restrict__ out, float* __restrict__ ws,
                                                const float* __restrict__ m,
                                                const float* __restrict__ lnw,
                                                const float* __restrict__ lnb,
                                                const float* __restrict__ part,
                                                const float* __restrict__ lnstats,
                                                u16* __restrict__ PCM)
{
    __shared__ __align__(16) u16 tl[64][136];   // [sp][128 ch + pad], 16B-aligned rows
    __shared__ float lst[5][64][2];             // LN3 stats for gates 1..5, this batch
    const int bi = blockIdx.x;
    const int b = bi >> 6;
    const int s0 = (bi & 63) << 6;

    // stage LN3 stats (gates 1..5) + re-reduce the 256 LN4 partials for this batch
    for (int j = threadIdx.x; j < 5 * 64; j += 256) {
        const int gg = j >> 6, chn = j & 63;
        lst[gg][chn][0] = lnstats[2 * ((gg + 1) * 512 + b * 64 + chn)];
        lst[gg][chn][1] = lnstats[2 * ((gg + 1) * 512 + b * 64 + chn) + 1];
    }
    float s  = part[b * 256 + threadIdx.x];
    float s2 = part[2048 + b * 256 + threadIdx.x];
    #pragma unroll
    for (int off = 32; off > 0; off >>= 1) { s += __shfl_down(s, off); s2 += __shfl_down(s2, off); }
    __shared__ float rs[4], rs2[4], st[2];
    if ((threadIdx.x & 63) == 0) { rs[threadIdx.x >> 6] = s; rs2[threadIdx.x >> 6] = s2; }
    __syncthreads();
    if (threadIdx.x == 0) {
        float S  = rs[0] + rs[1] + rs[2] + rs[3];
        float Sq = rs2[0] + rs2[1] + rs2[2] + rs2[3];
        float mu  = S * (1.f / CHB);
        float var = Sq * (1.f / CHB) - mu * mu;
        st[0] = mu; st[1] = rsqrtf(var + EPS);
    }
    __syncthreads();
    const float mu = st[0], rstd = st[1];

    for (int i = threadIdx.x; i < 1024; i += 256) {       // 64ch x 16 float4
        const int chn = i >> 4;
        const int sp4 = (i & 15) << 2;
        const size_t e = (size_t)b * CHB + (size_t)chn * SP + s0 + sp4;
        const size_t le = (size_t)chn * SP + s0 + sp4;
        float4 z  = *(const float4*)&ws[WS_Z_OFF + e];
        float4 u1 = *(const float4*)&gate_ptr(out, ws, 1)[e];
        float4 u2 = *(const float4*)&gate_ptr(out, ws, 2)[e];
        float4 u3 = *(const float4*)&gate_ptr(out, ws, 3)[e];
        float4 u4 = *(const float4*)&gate_ptr(out, ws, 4)[e];
        float4 u5 = *(const float4*)&gate_ptr(out, ws, 5)[e];
        float4 mm = *(const float4*)&m[e];
        float4 lw = *(const float4*)&lnw[le];
        float4 lb = *(const float4*)&lnb[le];
        const float m1 = lst[0][chn][0], r1 = lst[0][chn][1];
        const float m2 = lst[1][chn][0], r2 = lst[1][chn][1];
        const float m3 = lst[2][chn][0], r3 = lst[2][chn][1];
        const float m4 = lst[3][chn][0], r4 = lst[3][chn][1];
        const float m5 = lst[4][chn][0], r5 = lst[4][chn][1];
        float4 c, mn;
        {
            const float uu1[4] = {u1.x, u1.y, u1.z, u1.w};
            const float uu2[4] = {u2.x, u2.y, u2.z, u2.w};
            const float uu3[4] = {u3.x, u3.y, u3.z, u3.w};
            const float uu4[4] = {u4.x, u4.y, u4.z, u4.w};
            const float uu5[4] = {u5.x, u5.y, u5.z, u5.w};
            const float zz[4]  = {z.x, z.y, z.z, z.w};
            const float mmv[4] = {mm.x, mm.y, mm.z, mm.w};
            const float lwv[4] = {lw.x, lw.y, lw.z, lw.w};
            const float lbv[4] = {lb.x, lb.y, lb.z, lb.w};
            float cv[4], mv[4];
            #pragma unroll
            for (int k = 0; k < 4; ++k) {
                const float gi = fsig ((uu1[k] - m1) * r1);
                const float gg = ftanh((uu2[k] - m2) * r2);
                const float ip = fsig ((uu3[k] - m3) * r3);
                const float gp = ftanh((uu4[k] - m4) * r4);
                const float fp = fsig ((uu5[k] - m5) * r5);
                cv[k] = gi * gg + (zz[k] - mu) * rstd * lwv[k] + lbv[k];
                mv[k] = ip * gp + fp * mmv[k];
                tl[sp4 + k][chn]      = f2b(cv[k]);
                tl[sp4 + k][64 + chn] = f2b(mv[k]);
            }
            c.x = cv[0]; c.y = cv[1]; c.z = cv[2]; c.w = cv[3];
            mn.x = mv[0]; mn.y = mv[1]; mn.z = mv[2]; mn.w = mv[3];
        }
        *(float4*)&out[(size_t)4 * GATE_SZ + e] = c;
        *(float4*)&out[(size_t)5 * GATE_SZ + e] = mn;
    }
    __syncthreads();
    for (int j = threadIdx.x; j < 1024; j += 256) {       // 64 s x 16 ushort8
        const int sidx = j >> 4, c8 = (j & 15) << 3;
        ushort8 v = *(const ushort8*)&tl[sidx][c8];
        *(ushort8*)&PCM[((size_t)b * 4096 + s0 + sidx) * 128 + c8] = v;
    }
}

// ---- merged tail: hist copy AND h_new = sig(LN(u6)) * tanh(v) (o-gate LN fused) ----
// (b,chn) uniform per h_new block (1024 consecutive elems within one channel);
// u6 stats from ln6 (in ws Z region — tail never writes ws, so no race with the
// h_new write that overwrites slot-6 scratch in d_out).
__global__ __launch_bounds__(256) void tail_k(const float* __restrict__ chist,
                                              const float* __restrict__ u6,
                                              const float* __restrict__ v,
                                              const float* __restrict__ ln6,
                                              float* __restrict__ out)
{
    const int bi = blockIdx.x;
    if (bi < 8192) {
        const size_t i = (size_t)bi * 256 + threadIdx.x;
        ((float4*)out)[i] = ((const float4*)(chist + GATE_SZ))[i];
    } else {
        const int j = bi - 8192;
        const size_t e0 = (size_t)j * 1024;
        const int b   = (int)(e0 >> 18);          // CHB = 2^18
        const int chn = (int)((e0 >> 12) & 63);   // SP  = 2^12
        const float mu = ln6[2 * (b * 64 + chn)];
        const float rr = ln6[2 * (b * 64 + chn) + 1];
        const size_t i = (size_t)j * 256 + threadIdx.x;
        float4 uv = ((const float4*)u6)[i], vv = ((const float4*)v)[i];
        float4 r;
        r.x = fsig((uv.x - mu) * rr) * ftanh(vv.x);
        r.y = fsig((uv.y - mu) * rr) * ftanh(vv.y);
        r.z = fsig((uv.z - mu) * rr) * ftanh(vv.z);
        r.w = fsig((uv.w - mu) * rr) * ftanh(vv.w);
        ((float4*)(out + (size_t)6 * GATE_SZ))[i] = r;
    }
}

extern "C" void kernel_launch(void* const* d_in, const int* in_sizes, int n_in,
                              void* d_out, int out_size, void* d_ws, size_t ws_size,
                              hipStream_t stream)
{
    const float* x    = (const float*)d_in[0];
    const float* ch   = (const float*)d_in[1];
    const float* m    = (const float*)d_in[2];
    const float* h    = (const float*)d_in[3];
    const float* Wx   = (const float*)d_in[4];
    const float* bx   = (const float*)d_in[5];
    const float* Wh   = (const float*)d_in[6];
    const float* bh   = (const float*)d_in[7];
    const float* w111 = (const float*)d_in[8];
    const float* b111 = (const float*)d_in[9];
    const float* lnw  = (const float*)d_in[10];
    const float* lnb  = (const float*)d_in[11];
    float* out = (float*)d_out;
    float* ws  = (float*)d_ws;

    // Scratch placement in DEAD d_out slots:
    //   slot 0: u0 until scores_k; then PCM (8 MB); finally hist copy (tail).
    //   slot 4: XH, dead after MODE 0; rewritten by cm_pcm_k (c).
    //   slot 5: A7, dead after MODE 0; rewritten by cm_pcm_k (m_new).
    //   slot 6: XM + Ao/A111 + part (16 KB) + part2 (512 KB) + lnstatsA (24 KB);
    //           all readers finish before tail_k writes h_new over the slot.
    //   ws Z region head: ln6 (g6 stats, 2 KB) — written by lnred_B after MODE-1
    //   (Z dead post-cm_pcm), read by tail (which never writes ws). No race.
    u16* XH   = (u16*)(out + (size_t)4 * GATE_SZ);
    u16* A7   = (u16*)(out + (size_t)5 * GATE_SZ);
    u16* XM   = (u16*)(out + (size_t)6 * GATE_SZ);
    u16* Ao   = XM + (size_t)BATCH * 4096 * 96;      // behind XM, same slot
    u16* A111 = Ao + (size_t)NO;
    u16* PCM  = (u16*)out;                           // slot 0 (dead after scores_k)
    float* part     = (float*)(A111 + N1);           // 4096 floats
    float* p2s      = part + 4096;                   // 65536 floats
    float* p2s2     = p2s + NP2;                     // 65536 floats
    float* lnstatsA = p2s2 + NP2;                    // 6144 floats (gates 0..5)
    float* ln6      = ws + WS_Z_OFF;                 // 2048 floats (gate 6), in Z head
    float* stats    = ws + WS_ST_OFF;

    pack_w_k<<<(N7 + NO + N1 + 255) / 256, 256, 0, stream>>>(Wx, Wh, w111, A7, Ao, A111, stats);
    pack_xhm_k<<<512, 256, 0, stream>>>(x, h, m, XH, XM);

    // MODE 0: R0 core + contention-free LN3 partials (g<6)
    conv_mfma_k<96, 27, 2, 0, 4, 3><<<896, 256, 0, stream>>>(XH, XM, A7, bx, bh, nullptr, out, ws, p2s, p2s2);
    lnred_k<<<12, 256, 0, stream>>>(p2s, p2s2, lnstatsA, 0, 3072, 0);   // gates 0..5

    scores_k<<<512, 256, 0, stream>>>(out, ch, lnstatsA, stats);        // sigma(LN(u0)) inline
    recall_k<<<2048, 256, 0, stream>>>(ch, ws, part);                   // softmax fused, float4
    cm_pcm_k<<<512, 256, 0, stream>>>(out, ws, m, lnw, lnb, part, lnstatsA, PCM);

    // MODE 1: oc-split MT=2 -> 2 blocks/CU; epilogue writes g6 partials
    conv_mfma_k<128, 27, 1, 1, 2, 4><<<512, 256, 0, stream>>>(PCM, nullptr, Ao, nullptr, bh, nullptr, out, ws, p2s, p2s2);
    lnred_k<<<2, 256, 0, stream>>>(p2s, p2s2, ln6, 3072, 3584, 3072);   // gate 6
    // MODE 2: 1x1x1 conv -> v (ws slot 0)
    conv_mfma_k<128, 1, 1, 2, 4, 3><<<256, 256, 0, stream>>>(PCM, nullptr, A111, nullptr, nullptr, b111, out, ws, nullptr, nullptr);

    // tail: hist copy + h_new with o-gate LN+sigmoid fused (ln3_act_k eliminated)
    tail_k<<<10240, 256, 0, stream>>>(ch, ws + (size_t)2 * GATE_SZ, ws, ln6, out);
}